// Round 9
// baseline (376.907 us; speedup 1.0000x reference)
//
#include <hip/hip_runtime.h>
#include <stdint.h>

// VQ codebook assignment via split-precision bf16 MFMA:
//   argmin_k ||z-c_k||^2 == argmin_k (csq[k] - 2 z.c_k)
//   z.c ~= z_hi.c_hi + z_lo.c_hi + z_hi.c_lo   (bf16 hi/lo split, K_eff=768)
// Round-9: round-5 geometry (best so far, 60us) + in-register A-operand
// DOUBLE-BUFFER: step t's 24 MFMAs run while step t+1's 4 L2 codebook loads
// are in flight (prefetch crosses ct boundaries). Total regs ~116 <= 128 ->
// still 2 blocks/CU (16 waves). No barriers in main loop. fp64 fixup.

#define NQ 32768
#define ND 256
#define NK 1024
#define TAU 0.002f   // ~10 sigma of split-distance error; flags ~0.3% queries

typedef short bf16x8 __attribute__((ext_vector_type(8)));
typedef float f32x4  __attribute__((ext_vector_type(4)));

// ws layout (bytes); total ~1.19 MB
// cbw: ushort [64 koct][1024 codes][8]; koct 0..31 = c_hi octet, 32..63 = c_lo
#define WS_CBW 0
#define WS_CSQ (64 * 1024 * 8 * 2)       // 1 MB; then double csq[1024]
#define WS_CNT (WS_CSQ + 1024 * 8)
#define WS_LST (WS_CNT + 16)
#define WS_NEEDED (WS_LST + NQ * 4)

__device__ __forceinline__ ushort bf_trunc(float x) {
    return (ushort)(__builtin_bit_cast(uint32_t, x) >> 16);
}
__device__ __forceinline__ float bf_back(ushort h) {
    return __builtin_bit_cast(float, ((uint32_t)h) << 16);
}

// ---------------------------------------------------------------- prep ----
// 256 blocks x 256 threads; each wave converts one code row (4 codes/block).
__global__ __launch_bounds__(256)
void vq_prep(const float* __restrict__ cb, uint8_t* __restrict__ ws)
{
    ushort* cbw = (ushort*)(ws + WS_CBW);
    double* csq = (double*)(ws + WS_CSQ);
    int*    cnt = (int*)(ws + WS_CNT);

    const int tid  = threadIdx.x;
    const int code = blockIdx.x * 4 + (tid >> 6);
    const int lane = tid & 63;
    if (blockIdx.x == 0 && tid == 0) *cnt = 0;   // re-zero (determinism)

    const int d0 = lane * 4;
    const float4 v = *reinterpret_cast<const float4*>(&cb[(size_t)code * ND + d0]);
    const float xs[4] = {v.x, v.y, v.z, v.w};

    ushort4 h4, l4;
    ushort* hp = &h4.x; ushort* lp = &l4.x;
    double ss = 0.0;
    #pragma unroll
    for (int j = 0; j < 4; ++j) {
        const ushort h = bf_trunc(xs[j]);
        hp[j] = h;
        lp[j] = bf_trunc(xs[j] - bf_back(h));
        ss += (double)xs[j] * (double)xs[j];
    }

    const int oct = d0 >> 3;             // 0..31
    const int off = d0 & 7;              // 0 or 4
    *reinterpret_cast<ushort4*>(&cbw[((size_t)oct * NK + code) * 8 + off]) = h4;
    *reinterpret_cast<ushort4*>(&cbw[((size_t)(32 + oct) * NK + code) * 8 + off]) = l4;

    #pragma unroll
    for (int m = 1; m < 64; m <<= 1) ss += __shfl_xor(ss, m);
    if (lane == 0) csq[code] = ss;
}

// ---------------------------------------------------------------- main ----
// 512 threads = 8 waves; block = 64 queries x 1024 codes (4 code-tiles).
// Wave tile: 64 q x 32 codes (cm=2 code sub-tiles x qt=4 query tiles).
__global__ __launch_bounds__(512, 4)
void vq_main(const float* __restrict__ z, const float* __restrict__ cb,
             uint8_t* __restrict__ ws, float* __restrict__ out)
{
    __shared__ ushort zt[64][512];        // z hi(units 0..31)|lo(32..63), XOR-swizzled
    __shared__ float  csq_l[NK];
    __shared__ float  wb1[8][64], wb2[8][64];
    __shared__ int    wbi[8][64];
    __shared__ int    qidx[64];

    const ushort* cbw  = (const ushort*)(ws + WS_CBW);
    const double* csqd = (const double*)(ws + WS_CSQ);
    int* cnt = (int*)(ws + WS_CNT);
    int* lst = (int*)(ws + WS_LST);

    const int tid  = threadIdx.x;
    const int lane = tid & 63;
    const int w    = tid >> 6;            // wave 0..7 -> 32-code slice per ct
    const int cl   = lane & 15;
    const int g    = lane >> 4;           // quarter 0..3 (k-octet / code-row group)
    const int q0   = blockIdx.x * 64;

    // --- stage z tile: 64q x 256d fp32 -> hi/lo bf16, swizzled 16B units
    {
        const int rr = tid >> 6;
        const int c4 = (tid & 63) * 4;
        const int uh = c4 >> 3;           // hi unit 0..31
        const int ul = (256 + c4) >> 3;   // lo unit 32..63
        #pragma unroll
        for (int it = 0; it < 8; ++it) {
            const int q = it * 8 + rr;
            const float4 v = *reinterpret_cast<const float4*>(
                &z[(size_t)(q0 + q) * ND + c4]);
            const float xs[4] = {v.x, v.y, v.z, v.w};
            ushort4 h4, l4;
            ushort* hp = &h4.x; ushort* lp = &l4.x;
            #pragma unroll
            for (int j = 0; j < 4; ++j) {
                const ushort h = bf_trunc(xs[j]);
                hp[j] = h;
                lp[j] = bf_trunc(xs[j] - bf_back(h));
            }
            const int sw = q & 7;
            *reinterpret_cast<ushort4*>(&zt[q][((uh ^ sw) << 3) + (c4 & 7)]) = h4;
            *reinterpret_cast<ushort4*>(&zt[q][((ul ^ sw) << 3) + (c4 & 7)]) = l4;
        }
    }
    #pragma unroll
    for (int i = 0; i < 2; ++i)
        csq_l[i * 512 + tid] = (float)csqd[i * 512 + tid];
    __syncthreads();

    // per-lane running top-2, one slot per q-tile (q = qt*16 + cl)
    float b1[4], b2[4]; int bidx[4];
    #pragma unroll
    for (int s = 0; s < 4; ++s) { b1[s] = 3.0e38f; b2[s] = 3.0e38f; bidx[s] = 0; }

    // c-frag buffer layout: [0]=hi cm0, [1]=hi cm1, [2]=lo cm0, [3]=lo cm1
#define LOADC(BUF, T)                                                        \
    {                                                                        \
        const int ct_ = (T) >> 3;                                            \
        const int kk_ = (T) & 7;                                             \
        const int cb_ = ct_ * 256 + w * 32;                                  \
        const int oh_ = kk_ * 4 + g;                                         \
        _Pragma("unroll")                                                    \
        for (int cm = 0; cm < 2; ++cm) {                                     \
            const int code_ = cb_ + cm * 16 + cl;                            \
            BUF[cm] = *reinterpret_cast<const bf16x8*>(                      \
                &cbw[((size_t)oh_ * NK + code_) * 8]);                       \
            BUF[2 + cm] = *reinterpret_cast<const bf16x8*>(                  \
                &cbw[((size_t)(32 + oh_) * NK + code_) * 8]);                \
        }                                                                    \
    }
#define LOADZ(KK)                                                            \
    _Pragma("unroll")                                                        \
    for (int qt = 0; qt < 4; ++qt) {                                         \
        const int q_  = qt * 16 + cl;                                        \
        const int uh_ = ((KK) * 4 + g) ^ (q_ & 7);                           \
        const int ul_ = (32 + (KK) * 4 + g) ^ (q_ & 7);                      \
        zfh[qt] = *reinterpret_cast<const bf16x8*>(&zt[q_][uh_ << 3]);       \
        zfl[qt] = *reinterpret_cast<const bf16x8*>(&zt[q_][ul_ << 3]);       \
    }
#define DOMFMA(BUF)                                                          \
    _Pragma("unroll")                                                        \
    for (int cm = 0; cm < 2; ++cm)                                           \
        _Pragma("unroll")                                                    \
        for (int qt = 0; qt < 4; ++qt) {                                     \
            acc[cm][qt] = __builtin_amdgcn_mfma_f32_16x16x32_bf16(           \
                BUF[cm], zfh[qt], acc[cm][qt], 0, 0, 0);                     \
            acc[cm][qt] = __builtin_amdgcn_mfma_f32_16x16x32_bf16(           \
                BUF[cm], zfl[qt], acc[cm][qt], 0, 0, 0);                     \
            acc[cm][qt] = __builtin_amdgcn_mfma_f32_16x16x32_bf16(           \
                BUF[2 + cm], zfh[qt], acc[cm][qt], 0, 0, 0);                 \
        }

    bf16x8 cfA[4], cfB[4], zfh[4], zfl[4];
    LOADC(cfA, 0)                         // prologue: step 0 in flight

    #pragma unroll 1
    for (int ct = 0; ct < 4; ++ct) {
        f32x4 acc[2][4];                  // [cm][qt]
        #pragma unroll
        for (int cm = 0; cm < 2; ++cm)
            #pragma unroll
            for (int qt = 0; qt < 4; ++qt)
                acc[cm][qt] = (f32x4){0.f, 0.f, 0.f, 0.f};

        #pragma unroll
        for (int kk = 0; kk < 8; kk += 2) {
            const int t = ct * 8 + kk;
            LOADC(cfB, t + 1)             // prefetch: in flight under MFMA(A)
            LOADZ(kk)
            DOMFMA(cfA)
            if (t + 2 < 32) LOADC(cfA, t + 2)   // prefetch under MFMA(B)
            LOADZ(kk + 1)
            DOMFMA(cfB)
        }

        // fold this code-tile into the running top-2
        const int cbase = ct * 256 + w * 32;
        #pragma unroll
        for (int cm = 0; cm < 2; ++cm) {
            const int kb = cbase + cm * 16 + g * 4;
            const float4 cs4 = *reinterpret_cast<const float4*>(&csq_l[kb]);
            const float css[4] = {cs4.x, cs4.y, cs4.z, cs4.w};
            #pragma unroll
            for (int qt = 0; qt < 4; ++qt)
                #pragma unroll
                for (int r = 0; r < 4; ++r) {
                    const float d = fmaf(-2.0f, acc[cm][qt][r], css[r]);
                    if (d < b1[qt]) { b2[qt] = b1[qt]; b1[qt] = d; bidx[qt] = kb + r; }
                    else if (d < b2[qt]) b2[qt] = d;
                }
        }
    }
#undef LOADC
#undef LOADZ
#undef DOMFMA

    // --- combine the 4 quarters (same q = qt*16+cl, different codes)
    #pragma unroll
    for (int qt = 0; qt < 4; ++qt) {
        float B1 = b1[qt], B2 = b2[qt]; int BI = bidx[qt];
        #pragma unroll
        for (int m = 16; m < 64; m <<= 1) {
            const float o1 = __shfl_xor(B1, m);
            const float o2 = __shfl_xor(B2, m);
            const int   oi = __shfl_xor(BI, m);
            const float n2 = fminf(fmaxf(B1, o1), fminf(B2, o2));
            const bool sel = (o1 < B1) || (o1 == B1 && oi < BI);
            B1 = fminf(B1, o1); BI = sel ? oi : BI; B2 = n2;
        }
        if (g == 0) {
            const int q = qt * 16 + cl;
            wb1[w][q] = B1; wb2[w][q] = B2; wbi[w][q] = BI;
        }
    }
    __syncthreads();

    // --- combine 8 wave candidates, flag tight margins
    if (tid < 64) {
        float B1 = wb1[0][tid], B2 = wb2[0][tid]; int BI = wbi[0][tid];
        #pragma unroll
        for (int ww = 1; ww < 8; ++ww) {
            const float o1 = wb1[ww][tid], o2 = wb2[ww][tid];
            const int   oi = wbi[ww][tid];
            const float n2 = fminf(fmaxf(B1, o1), fminf(B2, o2));
            const bool sel = (o1 < B1) || (o1 == B1 && oi < BI);
            B1 = fminf(B1, o1); BI = sel ? oi : BI; B2 = n2;
        }
        qidx[tid] = BI;
        if (B2 - B1 < TAU) {
            const int pos = atomicAdd(cnt, 1);
            lst[pos] = q0 + tid;
        }
    }
    __syncthreads();

    // --- gather: out[q][:] = cb[idx[q]][:]
    {
        const int rr = tid >> 6;
        const int c  = (tid & 63) * 4;
        #pragma unroll
        for (int it = 0; it < 8; ++it) {
            const int q = it * 8 + rr;
            const int k = qidx[q];
            *reinterpret_cast<float4*>(&out[(size_t)(q0 + q) * ND + c]) =
                *reinterpret_cast<const float4*>(&cb[(size_t)k * ND + c]);
        }
    }
}

// --------------------------------------------------------------- fixup ----
// Exact fp64 re-solve for flagged (tight-margin) queries.
__global__ __launch_bounds__(256, 1)
void vq_fix(const float* __restrict__ z, const float* __restrict__ cb,
            uint8_t* __restrict__ ws, float* __restrict__ out)
{
    __shared__ double zd[ND];
    __shared__ double rb[256];
    __shared__ int    ri[256];

    const int* cnt = (const int*)(ws + WS_CNT);
    const int* lst = (const int*)(ws + WS_LST);
    const int tid = threadIdx.x;
    const int n = *cnt;

    for (int i = blockIdx.x; i < n; i += gridDim.x) {
        const int q = lst[i];
        __syncthreads();
        zd[tid] = (double)z[(size_t)q * ND + tid];
        __syncthreads();

        double best = 1.0e300; int bi = 0;
        #pragma unroll 1
        for (int j = 0; j < 4; ++j) {
            const int k = tid * 4 + j;
            double s = 0.0;
            const float* row = &cb[(size_t)k * ND];
            for (int d = 0; d < ND; ++d) {
                const double df = zd[d] - (double)row[d];
                s = fma(df, df, s);
            }
            if (s < best) { best = s; bi = k; }
        }
        rb[tid] = best; ri[tid] = bi;
        __syncthreads();
        for (int m = 128; m > 0; m >>= 1) {
            if (tid < m) {
                if (rb[tid + m] < rb[tid] ||
                    (rb[tid + m] == rb[tid] && ri[tid + m] < ri[tid])) {
                    rb[tid] = rb[tid + m]; ri[tid] = ri[tid + m];
                }
            }
            __syncthreads();
        }
        const int k = ri[0];
        if (tid < 64) {
            const float4 vv = *reinterpret_cast<const float4*>(
                &cb[(size_t)k * ND + tid * 4]);
            *reinterpret_cast<float4*>(&out[(size_t)q * ND + tid * 4]) = vv;
        }
        __syncthreads();
    }
}

// ------------------------------------------------- fallback (round-1) -----
// Verified-passing fp32 VALU kernel, used only if ws_size is insufficient.
__global__ __launch_bounds__(256, 2)
void vq_fallback(const float* __restrict__ z, const float* __restrict__ cb,
                 float* __restrict__ out)
{
    __shared__ float z_t[ND][64];
    __shared__ float cb_t[32][64];
    __shared__ float csq[NK];
    __shared__ int   idx_lds[64];

    const int tid = threadIdx.x;
    const int tx  = tid & 15;
    const int ty  = tid >> 4;
    const int q0  = blockIdx.x * 64;

    {
        const int r  = tid >> 6;
        const int c4 = (tid & 63) * 4;
        #pragma unroll
        for (int it = 0; it < 16; ++it) {
            const int q = it * 4 + r;
            const float4 v = *reinterpret_cast<const float4*>(
                &z[(size_t)(q0 + q) * ND + c4]);
            const float vv[4] = {v.x, v.y, v.z, v.w};
            #pragma unroll
            for (int j = 0; j < 4; ++j) {
                const int d = c4 + j;
                const int s = 4 * ((d >> 2) & 7);
                z_t[d][q ^ s] = vv[j];
            }
        }
    }
    {
        const int lane16 = tid & 15;
        const int rgrp   = tid >> 4;
        #pragma unroll 4
        for (int it = 0; it < 64; ++it) {
            const int k = it * 16 + rgrp;
            double ssum = 0.0;
            #pragma unroll
            for (int h = 0; h < 4; ++h) {
                const float4 v = *reinterpret_cast<const float4*>(
                    &cb[(size_t)k * ND + lane16 * 16 + h * 4]);
                ssum += (double)v.x * v.x + (double)v.y * v.y
                      + (double)v.z * v.z + (double)v.w * v.w;
            }
            #pragma unroll
            for (int m = 8; m >= 1; m >>= 1) ssum += __shfl_xor(ssum, m);
            if (lane16 == 0) csq[k] = (float)ssum;
        }
    }

    double bestd[4]; int besti[4];
    #pragma unroll
    for (int i = 0; i < 4; ++i) { bestd[i] = 1e300; besti[i] = 0; }

    for (int kt = 0; kt < 16; ++kt) {
        double acc[4][4];
        #pragma unroll
        for (int i = 0; i < 4; ++i)
            #pragma unroll
            for (int j = 0; j < 4; ++j) acc[i][j] = 0.0;

        for (int dc = 0; dc < 8; ++dc) {
            __syncthreads();
            {
                const int kk = tid >> 3;
                const int dd = (tid & 7) * 4;
                #pragma unroll
                for (int h = 0; h < 2; ++h) {
                    const int k = kk + h * 32;
                    const float4 v = *reinterpret_cast<const float4*>(
                        &cb[(size_t)(kt * 64 + k) * ND + dc * 32 + dd]);
                    const float vv[4] = {v.x, v.y, v.z, v.w};
                    #pragma unroll
                    for (int j = 0; j < 4; ++j) {
                        const int d = dd + j;
                        const int s = 4 * ((d >> 2) & 7);
                        cb_t[d][k ^ s] = vv[j];
                    }
                }
            }
            __syncthreads();

            float cr[4][4];
            #pragma unroll
            for (int i = 0; i < 4; ++i)
                #pragma unroll
                for (int j = 0; j < 4; ++j) cr[i][j] = 0.0f;

            #pragma unroll 8
            for (int d = 0; d < 32; ++d) {
                const int s  = 4 * ((d >> 2) & 7);
                const int dg = dc * 32 + d;
                const float4 zv4 = *reinterpret_cast<const float4*>(
                    &z_t[dg][(4 * ty) ^ s]);
                const float4 cv4 = *reinterpret_cast<const float4*>(
                    &cb_t[d][(4 * tx) ^ s]);
                const float zv[4] = {zv4.x, zv4.y, zv4.z, zv4.w};
                const float cv[4] = {cv4.x, cv4.y, cv4.z, cv4.w};
                #pragma unroll
                for (int i = 0; i < 4; ++i)
                    #pragma unroll
                    for (int j = 0; j < 4; ++j)
                        cr[i][j] = fmaf(zv[i], cv[j], cr[i][j]);
            }
            #pragma unroll
            for (int i = 0; i < 4; ++i)
                #pragma unroll
                for (int j = 0; j < 4; ++j)
                    acc[i][j] += (double)cr[i][j];
        }

        #pragma unroll
        for (int j = 0; j < 4; ++j) {
            const int k = kt * 64 + tx * 4 + j;
            const double cs = (double)csq[k];
            #pragma unroll
            for (int i = 0; i < 4; ++i) {
                const double dist = cs - 2.0 * acc[i][j];
                if (dist < bestd[i]) { bestd[i] = dist; besti[i] = k; }
            }
        }
    }

    #pragma unroll
    for (int i = 0; i < 4; ++i) {
        double bd = bestd[i]; int bi = besti[i];
        #pragma unroll
        for (int m = 8; m >= 1; m >>= 1) {
            const double od = __shfl_xor(bd, m);
            const int    oi = __shfl_xor(bi, m);
            if (od < bd || (od == bd && oi < bi)) { bd = od; bi = oi; }
        }
        if (tx == 0) idx_lds[ty * 4 + i] = bi;
    }
    __syncthreads();

    {
        const int r = tid >> 6;
        const int c = (tid & 63) * 4;
        #pragma unroll
        for (int it = 0; it < 16; ++it) {
            const int q = it * 4 + r;
            const int k = idx_lds[q];
            const float4 v = *reinterpret_cast<const float4*>(
                &cb[(size_t)k * ND + c]);
            *reinterpret_cast<float4*>(&out[(size_t)(q0 + q) * ND + c]) = v;
        }
    }
}

extern "C" void kernel_launch(void* const* d_in, const int* in_sizes, int n_in,
                              void* d_out, int out_size, void* d_ws, size_t ws_size,
                              hipStream_t stream)
{
    const float* z   = (const float*)d_in[0];   // [B,T,D] fp32
    const float* cbk = (const float*)d_in[1];   // [K,D]  fp32
    float* out = (float*)d_out;
    uint8_t* ws = (uint8_t*)d_ws;

    if (ws_size < (size_t)WS_NEEDED) {
        vq_fallback<<<NQ / 64, 256, 0, stream>>>(z, cbk, out);
        return;
    }

    vq_prep<<<NK / 4, 256, 0, stream>>>(cbk, ws);
    vq_main<<<NQ / 64, 512, 0, stream>>>(z, cbk, ws, out);
    vq_fix<<<128, 256, 0, stream>>>(z, cbk, ws, out);
}

// Round 10
// 98.547 us; speedup vs baseline: 3.8246x; 3.8246x over previous
//
#include <hip/hip_runtime.h>
#include <stdint.h>

// VQ codebook assignment via split-precision bf16 MFMA:
//   argmin_k ||z-c_k||^2 == argmin_k (csq[k] - 2 z.c_k)
//   z.c ~= z_hi.c_hi + z_lo.c_hi + z_hi.c_lo   (bf16 hi/lo split, K_eff=768)
// Round-10: round-5 geometry (60us verified) + c-frag rotate pipeline with
// STRICT liveness control: kk loop unroll 1 (double-steps), zf arrays scoped
// inside the body, prologue cf load hoisted above staging. ~121 regs <= 128
// budget of (512,4) -> no spill (tripwire: WRITE_SIZE ~33MB). setprio around
// MFMA clusters (independent waves -> T5 regime). fp64 fixup, TAU=0.002.

#define NQ 32768
#define ND 256
#define NK 1024
#define TAU 0.002f   // ~20 sigma of split-distance error

typedef short bf16x8 __attribute__((ext_vector_type(8)));
typedef float f32x4  __attribute__((ext_vector_type(4)));

// ws layout (bytes); total ~1.19 MB
// cbw: ushort [64 koct][1024 codes][8]; koct 0..31 = c_hi octet, 32..63 = c_lo
#define WS_CBW 0
#define WS_CSQ (64 * 1024 * 8 * 2)       // 1 MB; then double csq[1024]
#define WS_CNT (WS_CSQ + 1024 * 8)
#define WS_LST (WS_CNT + 16)
#define WS_NEEDED (WS_LST + NQ * 4)

__device__ __forceinline__ ushort bf_trunc(float x) {
    return (ushort)(__builtin_bit_cast(uint32_t, x) >> 16);
}
__device__ __forceinline__ float bf_back(ushort h) {
    return __builtin_bit_cast(float, ((uint32_t)h) << 16);
}

// ---------------------------------------------------------------- prep ----
// 256 blocks x 256 threads; each wave converts one code row (4 codes/block).
__global__ __launch_bounds__(256)
void vq_prep(const float* __restrict__ cb, uint8_t* __restrict__ ws)
{
    ushort* cbw = (ushort*)(ws + WS_CBW);
    double* csq = (double*)(ws + WS_CSQ);
    int*    cnt = (int*)(ws + WS_CNT);

    const int tid  = threadIdx.x;
    const int code = blockIdx.x * 4 + (tid >> 6);
    const int lane = tid & 63;
    if (blockIdx.x == 0 && tid == 0) *cnt = 0;   // re-zero (determinism)

    const int d0 = lane * 4;
    const float4 v = *reinterpret_cast<const float4*>(&cb[(size_t)code * ND + d0]);
    const float xs[4] = {v.x, v.y, v.z, v.w};

    ushort4 h4, l4;
    ushort* hp = &h4.x; ushort* lp = &l4.x;
    double ss = 0.0;
    #pragma unroll
    for (int j = 0; j < 4; ++j) {
        const ushort h = bf_trunc(xs[j]);
        hp[j] = h;
        lp[j] = bf_trunc(xs[j] - bf_back(h));
        ss += (double)xs[j] * (double)xs[j];
    }

    const int oct = d0 >> 3;             // 0..31
    const int off = d0 & 7;              // 0 or 4
    *reinterpret_cast<ushort4*>(&cbw[((size_t)oct * NK + code) * 8 + off]) = h4;
    *reinterpret_cast<ushort4*>(&cbw[((size_t)(32 + oct) * NK + code) * 8 + off]) = l4;

    #pragma unroll
    for (int m = 1; m < 64; m <<= 1) ss += __shfl_xor(ss, m);
    if (lane == 0) csq[code] = ss;
}

// ---------------------------------------------------------------- main ----
// 512 threads = 8 waves; block = 64 queries x 1024 codes (4 code-tiles).
// Wave tile: 64 q x 32 codes (cm=2 code sub-tiles x qt=4 query tiles).
__global__ __launch_bounds__(512, 4)
void vq_main(const float* __restrict__ z, const float* __restrict__ cb,
             uint8_t* __restrict__ ws, float* __restrict__ out)
{
    __shared__ ushort zt[64][512];        // z hi(units 0..31)|lo(32..63), XOR-swizzled
    __shared__ float  csq_l[NK];
    __shared__ float  wb1[8][64], wb2[8][64];
    __shared__ int    wbi[8][64];
    __shared__ int    qidx[64];

    const ushort* cbw  = (const ushort*)(ws + WS_CBW);
    const double* csqd = (const double*)(ws + WS_CSQ);
    int* cnt = (int*)(ws + WS_CNT);
    int* lst = (int*)(ws + WS_LST);

    const int tid  = threadIdx.x;
    const int lane = tid & 63;
    const int w    = tid >> 6;            // wave 0..7 -> 32-code slice per ct
    const int cl   = lane & 15;
    const int g    = lane >> 4;           // quarter 0..3 (k-octet / code-row group)
    const int q0   = blockIdx.x * 64;

    // c-frag buffer layout: [0]=hi cm0, [1]=hi cm1, [2]=lo cm0, [3]=lo cm1
#define LOADC(BUF, T)                                                        \
    {                                                                        \
        const int ct_ = (T) >> 3;                                            \
        const int kk_ = (T) & 7;                                             \
        const int cb_ = ct_ * 256 + w * 32;                                  \
        const int oh_ = kk_ * 4 + g;                                         \
        _Pragma("unroll")                                                    \
        for (int cm = 0; cm < 2; ++cm) {                                     \
            const int code_ = cb_ + cm * 16 + cl;                            \
            BUF[cm] = *reinterpret_cast<const bf16x8*>(                      \
                &cbw[((size_t)oh_ * NK + code_) * 8]);                       \
            BUF[2 + cm] = *reinterpret_cast<const bf16x8*>(                  \
                &cbw[((size_t)(32 + oh_) * NK + code_) * 8]);                \
        }                                                                    \
    }
#define LOADZ(KK)                                                            \
    _Pragma("unroll")                                                        \
    for (int qt = 0; qt < 4; ++qt) {                                         \
        const int q_  = qt * 16 + cl;                                        \
        const int uh_ = ((KK) * 4 + g) ^ (q_ & 7);                           \
        const int ul_ = (32 + (KK) * 4 + g) ^ (q_ & 7);                      \
        zfh[qt] = *reinterpret_cast<const bf16x8*>(&zt[q_][uh_ << 3]);       \
        zfl[qt] = *reinterpret_cast<const bf16x8*>(&zt[q_][ul_ << 3]);       \
    }
#define DOMFMA(BUF)                                                          \
    __builtin_amdgcn_s_setprio(1);                                           \
    _Pragma("unroll")                                                        \
    for (int cm = 0; cm < 2; ++cm)                                           \
        _Pragma("unroll")                                                    \
        for (int qt = 0; qt < 4; ++qt) {                                     \
            acc[cm][qt] = __builtin_amdgcn_mfma_f32_16x16x32_bf16(           \
                BUF[cm], zfh[qt], acc[cm][qt], 0, 0, 0);                     \
            acc[cm][qt] = __builtin_amdgcn_mfma_f32_16x16x32_bf16(           \
                BUF[cm], zfl[qt], acc[cm][qt], 0, 0, 0);                     \
            acc[cm][qt] = __builtin_amdgcn_mfma_f32_16x16x32_bf16(           \
                BUF[2 + cm], zfh[qt], acc[cm][qt], 0, 0, 0);                 \
        }                                                                    \
    __builtin_amdgcn_s_setprio(0);

    bf16x8 cfA[4], cfB[4];
    LOADC(cfA, 0)                         // prologue: hides under z-staging

    // --- stage z tile: 64q x 256d fp32 -> hi/lo bf16, swizzled 16B units
    {
        const int rr = tid >> 6;
        const int c4 = (tid & 63) * 4;
        const int uh = c4 >> 3;           // hi unit 0..31
        const int ul = (256 + c4) >> 3;   // lo unit 32..63
        #pragma unroll
        for (int it = 0; it < 8; ++it) {
            const int q = it * 8 + rr;
            const float4 v = *reinterpret_cast<const float4*>(
                &z[(size_t)(q0 + q) * ND + c4]);
            const float xs[4] = {v.x, v.y, v.z, v.w};
            ushort4 h4, l4;
            ushort* hp = &h4.x; ushort* lp = &l4.x;
            #pragma unroll
            for (int j = 0; j < 4; ++j) {
                const ushort h = bf_trunc(xs[j]);
                hp[j] = h;
                lp[j] = bf_trunc(xs[j] - bf_back(h));
            }
            const int sw = q & 7;
            *reinterpret_cast<ushort4*>(&zt[q][((uh ^ sw) << 3) + (c4 & 7)]) = h4;
            *reinterpret_cast<ushort4*>(&zt[q][((ul ^ sw) << 3) + (c4 & 7)]) = l4;
        }
    }
    #pragma unroll
    for (int i = 0; i < 2; ++i)
        csq_l[i * 512 + tid] = (float)csqd[i * 512 + tid];
    __syncthreads();

    // per-lane running top-2, one slot per q-tile (q = qt*16 + cl)
    float b1[4], b2[4]; int bidx[4];
    #pragma unroll
    for (int s = 0; s < 4; ++s) { b1[s] = 3.0e38f; b2[s] = 3.0e38f; bidx[s] = 0; }

    #pragma unroll 1
    for (int ct = 0; ct < 4; ++ct) {
        f32x4 acc[2][4];                  // [cm][qt]
        #pragma unroll
        for (int cm = 0; cm < 2; ++cm)
            #pragma unroll
            for (int qt = 0; qt < 4; ++qt)
                acc[cm][qt] = (f32x4){0.f, 0.f, 0.f, 0.f};

        #pragma unroll 1
        for (int kk = 0; kk < 8; kk += 2) {
            const int t = ct * 8 + kk;
            bf16x8 zfh[4], zfl[4];
            LOADC(cfB, t + 1)             // in flight under MFMA(cfA)
            LOADZ(kk)
            DOMFMA(cfA)
            if (t + 2 < 32) LOADC(cfA, t + 2)   // in flight under MFMA(cfB)
            LOADZ(kk + 1)
            DOMFMA(cfB)
        }

        // fold this code-tile into the running top-2
        const int cbase = ct * 256 + w * 32;
        #pragma unroll
        for (int cm = 0; cm < 2; ++cm) {
            const int kb = cbase + cm * 16 + g * 4;
            const float4 cs4 = *reinterpret_cast<const float4*>(&csq_l[kb]);
            const float css[4] = {cs4.x, cs4.y, cs4.z, cs4.w};
            #pragma unroll
            for (int qt = 0; qt < 4; ++qt)
                #pragma unroll
                for (int r = 0; r < 4; ++r) {
                    const float d = fmaf(-2.0f, acc[cm][qt][r], css[r]);
                    if (d < b1[qt]) { b2[qt] = b1[qt]; b1[qt] = d; bidx[qt] = kb + r; }
                    else if (d < b2[qt]) b2[qt] = d;
                }
        }
    }
#undef LOADC
#undef LOADZ
#undef DOMFMA

    // --- combine the 4 quarters (same q = qt*16+cl, different codes)
    #pragma unroll
    for (int qt = 0; qt < 4; ++qt) {
        float B1 = b1[qt], B2 = b2[qt]; int BI = bidx[qt];
        #pragma unroll
        for (int m = 16; m < 64; m <<= 1) {
            const float o1 = __shfl_xor(B1, m);
            const float o2 = __shfl_xor(B2, m);
            const int   oi = __shfl_xor(BI, m);
            const float n2 = fminf(fmaxf(B1, o1), fminf(B2, o2));
            const bool sel = (o1 < B1) || (o1 == B1 && oi < BI);
            B1 = fminf(B1, o1); BI = sel ? oi : BI; B2 = n2;
        }
        if (g == 0) {
            const int q = qt * 16 + cl;
            wb1[w][q] = B1; wb2[w][q] = B2; wbi[w][q] = BI;
        }
    }
    __syncthreads();

    // --- combine 8 wave candidates, flag tight margins
    if (tid < 64) {
        float B1 = wb1[0][tid], B2 = wb2[0][tid]; int BI = wbi[0][tid];
        #pragma unroll
        for (int ww = 1; ww < 8; ++ww) {
            const float o1 = wb1[ww][tid], o2 = wb2[ww][tid];
            const int   oi = wbi[ww][tid];
            const float n2 = fminf(fmaxf(B1, o1), fminf(B2, o2));
            const bool sel = (o1 < B1) || (o1 == B1 && oi < BI);
            B1 = fminf(B1, o1); BI = sel ? oi : BI; B2 = n2;
        }
        qidx[tid] = BI;
        if (B2 - B1 < TAU) {
            const int pos = atomicAdd(cnt, 1);
            lst[pos] = q0 + tid;
        }
    }
    __syncthreads();

    // --- gather: out[q][:] = cb[idx[q]][:]
    {
        const int rr = tid >> 6;
        const int c  = (tid & 63) * 4;
        #pragma unroll
        for (int it = 0; it < 8; ++it) {
            const int q = it * 8 + rr;
            const int k = qidx[q];
            *reinterpret_cast<float4*>(&out[(size_t)(q0 + q) * ND + c]) =
                *reinterpret_cast<const float4*>(&cb[(size_t)k * ND + c]);
        }
    }
}

// --------------------------------------------------------------- fixup ----
// Exact fp64 re-solve for flagged (tight-margin) queries.
__global__ __launch_bounds__(256, 1)
void vq_fix(const float* __restrict__ z, const float* __restrict__ cb,
            uint8_t* __restrict__ ws, float* __restrict__ out)
{
    __shared__ double zd[ND];
    __shared__ double rb[256];
    __shared__ int    ri[256];

    const int* cnt = (const int*)(ws + WS_CNT);
    const int* lst = (const int*)(ws + WS_LST);
    const int tid = threadIdx.x;
    const int n = *cnt;

    for (int i = blockIdx.x; i < n; i += gridDim.x) {
        const int q = lst[i];
        __syncthreads();
        zd[tid] = (double)z[(size_t)q * ND + tid];
        __syncthreads();

        double best = 1.0e300; int bi = 0;
        #pragma unroll 1
        for (int j = 0; j < 4; ++j) {
            const int k = tid * 4 + j;
            double s = 0.0;
            const float* row = &cb[(size_t)k * ND];
            for (int d = 0; d < ND; ++d) {
                const double df = zd[d] - (double)row[d];
                s = fma(df, df, s);
            }
            if (s < best) { best = s; bi = k; }
        }
        rb[tid] = best; ri[tid] = bi;
        __syncthreads();
        for (int m = 128; m > 0; m >>= 1) {
            if (tid < m) {
                if (rb[tid + m] < rb[tid] ||
                    (rb[tid + m] == rb[tid] && ri[tid + m] < ri[tid])) {
                    rb[tid] = rb[tid + m]; ri[tid] = ri[tid + m];
                }
            }
            __syncthreads();
        }
        const int k = ri[0];
        if (tid < 64) {
            const float4 vv = *reinterpret_cast<const float4*>(
                &cb[(size_t)k * ND + tid * 4]);
            *reinterpret_cast<float4*>(&out[(size_t)q * ND + tid * 4]) = vv;
        }
        __syncthreads();
    }
}

// ------------------------------------------------- fallback (round-1) -----
// Verified-passing fp32 VALU kernel, used only if ws_size is insufficient.
__global__ __launch_bounds__(256, 2)
void vq_fallback(const float* __restrict__ z, const float* __restrict__ cb,
                 float* __restrict__ out)
{
    __shared__ float z_t[ND][64];
    __shared__ float cb_t[32][64];
    __shared__ float csq[NK];
    __shared__ int   idx_lds[64];

    const int tid = threadIdx.x;
    const int tx  = tid & 15;
    const int ty  = tid >> 4;
    const int q0  = blockIdx.x * 64;

    {
        const int r  = tid >> 6;
        const int c4 = (tid & 63) * 4;
        #pragma unroll
        for (int it = 0; it < 16; ++it) {
            const int q = it * 4 + r;
            const float4 v = *reinterpret_cast<const float4*>(
                &z[(size_t)(q0 + q) * ND + c4]);
            const float vv[4] = {v.x, v.y, v.z, v.w};
            #pragma unroll
            for (int j = 0; j < 4; ++j) {
                const int d = c4 + j;
                const int s = 4 * ((d >> 2) & 7);
                z_t[d][q ^ s] = vv[j];
            }
        }
    }
    {
        const int lane16 = tid & 15;
        const int rgrp   = tid >> 4;
        #pragma unroll 4
        for (int it = 0; it < 64; ++it) {
            const int k = it * 16 + rgrp;
            double ssum = 0.0;
            #pragma unroll
            for (int h = 0; h < 4; ++h) {
                const float4 v = *reinterpret_cast<const float4*>(
                    &cb[(size_t)k * ND + lane16 * 16 + h * 4]);
                ssum += (double)v.x * v.x + (double)v.y * v.y
                      + (double)v.z * v.z + (double)v.w * v.w;
            }
            #pragma unroll
            for (int m = 8; m >= 1; m >>= 1) ssum += __shfl_xor(ssum, m);
            if (lane16 == 0) csq[k] = (float)ssum;
        }
    }

    double bestd[4]; int besti[4];
    #pragma unroll
    for (int i = 0; i < 4; ++i) { bestd[i] = 1e300; besti[i] = 0; }

    for (int kt = 0; kt < 16; ++kt) {
        double acc[4][4];
        #pragma unroll
        for (int i = 0; i < 4; ++i)
            #pragma unroll
            for (int j = 0; j < 4; ++j) acc[i][j] = 0.0;

        for (int dc = 0; dc < 8; ++dc) {
            __syncthreads();
            {
                const int kk = tid >> 3;
                const int dd = (tid & 7) * 4;
                #pragma unroll
                for (int h = 0; h < 2; ++h) {
                    const int k = kk + h * 32;
                    const float4 v = *reinterpret_cast<const float4*>(
                        &cb[(size_t)(kt * 64 + k) * ND + dc * 32 + dd]);
                    const float vv[4] = {v.x, v.y, v.z, v.w};
                    #pragma unroll
                    for (int j = 0; j < 4; ++j) {
                        const int d = dd + j;
                        const int s = 4 * ((d >> 2) & 7);
                        cb_t[d][k ^ s] = vv[j];
                    }
                }
            }
            __syncthreads();

            float cr[4][4];
            #pragma unroll
            for (int i = 0; i < 4; ++i)
                #pragma unroll
                for (int j = 0; j < 4; ++j) cr[i][j] = 0.0f;

            #pragma unroll 8
            for (int d = 0; d < 32; ++d) {
                const int s  = 4 * ((d >> 2) & 7);
                const int dg = dc * 32 + d;
                const float4 zv4 = *reinterpret_cast<const float4*>(
                    &z_t[dg][(4 * ty) ^ s]);
                const float4 cv4 = *reinterpret_cast<const float4*>(
                    &cb_t[d][(4 * tx) ^ s]);
                const float zv[4] = {zv4.x, zv4.y, zv4.z, zv4.w};
                const float cv[4] = {cv4.x, cv4.y, cv4.z, cv4.w};
                #pragma unroll
                for (int i = 0; i < 4; ++i)
                    #pragma unroll
                    for (int j = 0; j < 4; ++j)
                        cr[i][j] = fmaf(zv[i], cv[j], cr[i][j]);
            }
            #pragma unroll
            for (int i = 0; i < 4; ++i)
                #pragma unroll
                for (int j = 0; j < 4; ++j)
                    acc[i][j] += (double)cr[i][j];
        }

        #pragma unroll
        for (int j = 0; j < 4; ++j) {
            const int k = kt * 64 + tx * 4 + j;
            const double cs = (double)csq[k];
            #pragma unroll
            for (int i = 0; i < 4; ++i) {
                const double dist = cs - 2.0 * acc[i][j];
                if (dist < bestd[i]) { bestd[i] = dist; besti[i] = k; }
            }
        }
    }

    #pragma unroll
    for (int i = 0; i < 4; ++i) {
        double bd = bestd[i]; int bi = besti[i];
        #pragma unroll
        for (int m = 8; m >= 1; m >>= 1) {
            const double od = __shfl_xor(bd, m);
            const int    oi = __shfl_xor(bi, m);
            if (od < bd || (od == bd && oi < bi)) { bd = od; bi = oi; }
        }
        if (tx == 0) idx_lds[ty * 4 + i] = bi;
    }
    __syncthreads();

    {
        const int r = tid >> 6;
        const int c = (tid & 63) * 4;
        #pragma unroll
        for (int it = 0; it < 16; ++it) {
            const int q = it * 4 + r;
            const int k = idx_lds[q];
            const float4 v = *reinterpret_cast<const float4*>(
                &cb[(size_t)k * ND + c]);
            *reinterpret_cast<float4*>(&out[(size_t)(q0 + q) * ND + c]) = v;
        }
    }
}

extern "C" void kernel_launch(void* const* d_in, const int* in_sizes, int n_in,
                              void* d_out, int out_size, void* d_ws, size_t ws_size,
                              hipStream_t stream)
{
    const float* z   = (const float*)d_in[0];   // [B,T,D] fp32
    const float* cbk = (const float*)d_in[1];   // [K,D]  fp32
    float* out = (float*)d_out;
    uint8_t* ws = (uint8_t*)d_ws;

    if (ws_size < (size_t)WS_NEEDED) {
        vq_fallback<<<NQ / 64, 256, 0, stream>>>(z, cbk, out);
        return;
    }

    vq_prep<<<NK / 4, 256, 0, stream>>>(cbk, ws);
    vq_main<<<NQ / 64, 512, 0, stream>>>(z, cbk, ws, out);
    vq_fix<<<128, 256, 0, stream>>>(z, cbk, ws, out);
}

// Round 11
// 92.657 us; speedup vs baseline: 4.0678x; 1.0636x over previous
//
#include <hip/hip_runtime.h>
#include <stdint.h>

// VQ codebook assignment via split-precision bf16 MFMA:
//   argmin_k ||z-c_k||^2 == argmin_k (csq[k] - 2 z.c_k)
//   z.c ~= z_hi.c_hi + z_lo.c_hi + z_hi.c_lo   (bf16 hi/lo split, K_eff=768)
// Round-11: r10 main (60.7us verified) + FUSED fp64 fixup tail — flagged
// (margin < TAU) queries re-solved exactly inside the same block using LDS
// scratch carved from the dead z-tile. vq_fix kernel and ws cnt/lst removed;
// graph = prep -> main. Gather skips flagged rows (store-order safety).

#define NQ 32768
#define ND 256
#define NK 1024
#define TAU 0.002f   // margin threshold for the exact-fixup path

typedef short bf16x8 __attribute__((ext_vector_type(8)));
typedef float f32x4  __attribute__((ext_vector_type(4)));

// ws layout (bytes); ~1.06 MB
// cbw: ushort [64 koct][1024 codes][8]; koct 0..31 = c_hi octet, 32..63 = c_lo
#define WS_CBW 0
#define WS_CSQ (64 * 1024 * 8 * 2)       // 1 MB; then double csq[1024]
#define WS_NEEDED (WS_CSQ + 1024 * 8)

__device__ __forceinline__ ushort bf_trunc(float x) {
    return (ushort)(__builtin_bit_cast(uint32_t, x) >> 16);
}
__device__ __forceinline__ float bf_back(ushort h) {
    return __builtin_bit_cast(float, ((uint32_t)h) << 16);
}

// ---------------------------------------------------------------- prep ----
// 256 blocks x 256 threads; each wave converts one code row (4 codes/block).
__global__ __launch_bounds__(256)
void vq_prep(const float* __restrict__ cb, uint8_t* __restrict__ ws)
{
    ushort* cbw = (ushort*)(ws + WS_CBW);
    double* csq = (double*)(ws + WS_CSQ);

    const int tid  = threadIdx.x;
    const int code = blockIdx.x * 4 + (tid >> 6);
    const int lane = tid & 63;

    const int d0 = lane * 4;
    const float4 v = *reinterpret_cast<const float4*>(&cb[(size_t)code * ND + d0]);
    const float xs[4] = {v.x, v.y, v.z, v.w};

    ushort4 h4, l4;
    ushort* hp = &h4.x; ushort* lp = &l4.x;
    double ss = 0.0;
    #pragma unroll
    for (int j = 0; j < 4; ++j) {
        const ushort h = bf_trunc(xs[j]);
        hp[j] = h;
        lp[j] = bf_trunc(xs[j] - bf_back(h));
        ss += (double)xs[j] * (double)xs[j];
    }

    const int oct = d0 >> 3;             // 0..31
    const int off = d0 & 7;              // 0 or 4
    *reinterpret_cast<ushort4*>(&cbw[((size_t)oct * NK + code) * 8 + off]) = h4;
    *reinterpret_cast<ushort4*>(&cbw[((size_t)(32 + oct) * NK + code) * 8 + off]) = l4;

    #pragma unroll
    for (int m = 1; m < 64; m <<= 1) ss += __shfl_xor(ss, m);
    if (lane == 0) csq[code] = ss;
}

// ---------------------------------------------------------------- main ----
// 512 threads = 8 waves; block = 64 queries x 1024 codes (4 code-tiles).
// Wave tile: 64 q x 32 codes (cm=2 code sub-tiles x qt=4 query tiles).
__global__ __launch_bounds__(512, 4)
void vq_main(const float* __restrict__ z, const float* __restrict__ cb,
             uint8_t* __restrict__ ws, float* __restrict__ out)
{
    __shared__ alignas(16) ushort zt[64][512];  // z hi|lo, XOR-swizzled (64KB)
    __shared__ float  csq_l[NK];
    __shared__ float  wb1[8][64], wb2[8][64];
    __shared__ int    wbi[8][64];
    __shared__ int    qidx[64];
    __shared__ int    qf[64];             // flagged local q list
    __shared__ int    flagged[64];        // per-q flag (gather skips these)
    __shared__ int    nf;

    const ushort* cbw  = (const ushort*)(ws + WS_CBW);
    const double* csqd = (const double*)(ws + WS_CSQ);

    const int tid  = threadIdx.x;
    const int lane = tid & 63;
    const int w    = tid >> 6;            // wave 0..7 -> 32-code slice per ct
    const int cl   = lane & 15;
    const int g    = lane >> 4;           // quarter 0..3 (k-octet / code-row group)
    const int q0   = blockIdx.x * 64;

    if (tid == 0) nf = 0;
    if (tid < 64) flagged[tid] = 0;

    // c-frag buffer layout: [0]=hi cm0, [1]=hi cm1, [2]=lo cm0, [3]=lo cm1
#define LOADC(BUF, T)                                                        \
    {                                                                        \
        const int ct_ = (T) >> 3;                                            \
        const int kk_ = (T) & 7;                                             \
        const int cb_ = ct_ * 256 + w * 32;                                  \
        const int oh_ = kk_ * 4 + g;                                         \
        _Pragma("unroll")                                                    \
        for (int cm = 0; cm < 2; ++cm) {                                     \
            const int code_ = cb_ + cm * 16 + cl;                            \
            BUF[cm] = *reinterpret_cast<const bf16x8*>(                      \
                &cbw[((size_t)oh_ * NK + code_) * 8]);                       \
            BUF[2 + cm] = *reinterpret_cast<const bf16x8*>(                  \
                &cbw[((size_t)(32 + oh_) * NK + code_) * 8]);                \
        }                                                                    \
    }
#define LOADZ(KK)                                                            \
    _Pragma("unroll")                                                        \
    for (int qt = 0; qt < 4; ++qt) {                                         \
        const int q_  = qt * 16 + cl;                                        \
        const int uh_ = ((KK) * 4 + g) ^ (q_ & 7);                           \
        const int ul_ = (32 + (KK) * 4 + g) ^ (q_ & 7);                      \
        zfh[qt] = *reinterpret_cast<const bf16x8*>(&zt[q_][uh_ << 3]);       \
        zfl[qt] = *reinterpret_cast<const bf16x8*>(&zt[q_][ul_ << 3]);       \
    }
#define DOMFMA(BUF)                                                          \
    __builtin_amdgcn_s_setprio(1);                                           \
    _Pragma("unroll")                                                        \
    for (int cm = 0; cm < 2; ++cm)                                           \
        _Pragma("unroll")                                                    \
        for (int qt = 0; qt < 4; ++qt) {                                     \
            acc[cm][qt] = __builtin_amdgcn_mfma_f32_16x16x32_bf16(           \
                BUF[cm], zfh[qt], acc[cm][qt], 0, 0, 0);                     \
            acc[cm][qt] = __builtin_amdgcn_mfma_f32_16x16x32_bf16(           \
                BUF[cm], zfl[qt], acc[cm][qt], 0, 0, 0);                     \
            acc[cm][qt] = __builtin_amdgcn_mfma_f32_16x16x32_bf16(           \
                BUF[2 + cm], zfh[qt], acc[cm][qt], 0, 0, 0);                 \
        }                                                                    \
    __builtin_amdgcn_s_setprio(0);

    bf16x8 cfA[4], cfB[4];
    LOADC(cfA, 0)                         // prologue: hides under z-staging

    // --- stage z tile: 64q x 256d fp32 -> hi/lo bf16, swizzled 16B units
    {
        const int rr = tid >> 6;
        const int c4 = (tid & 63) * 4;
        const int uh = c4 >> 3;           // hi unit 0..31
        const int ul = (256 + c4) >> 3;   // lo unit 32..63
        #pragma unroll
        for (int it = 0; it < 8; ++it) {
            const int q = it * 8 + rr;
            const float4 v = *reinterpret_cast<const float4*>(
                &z[(size_t)(q0 + q) * ND + c4]);
            const float xs[4] = {v.x, v.y, v.z, v.w};
            ushort4 h4, l4;
            ushort* hp = &h4.x; ushort* lp = &l4.x;
            #pragma unroll
            for (int j = 0; j < 4; ++j) {
                const ushort h = bf_trunc(xs[j]);
                hp[j] = h;
                lp[j] = bf_trunc(xs[j] - bf_back(h));
            }
            const int sw = q & 7;
            *reinterpret_cast<ushort4*>(&zt[q][((uh ^ sw) << 3) + (c4 & 7)]) = h4;
            *reinterpret_cast<ushort4*>(&zt[q][((ul ^ sw) << 3) + (c4 & 7)]) = l4;
        }
    }
    #pragma unroll
    for (int i = 0; i < 2; ++i)
        csq_l[i * 512 + tid] = (float)csqd[i * 512 + tid];
    __syncthreads();

    // per-lane running top-2, one slot per q-tile (q = qt*16 + cl)
    float b1[4], b2[4]; int bidx[4];
    #pragma unroll
    for (int s = 0; s < 4; ++s) { b1[s] = 3.0e38f; b2[s] = 3.0e38f; bidx[s] = 0; }

    #pragma unroll 1
    for (int ct = 0; ct < 4; ++ct) {
        f32x4 acc[2][4];                  // [cm][qt]
        #pragma unroll
        for (int cm = 0; cm < 2; ++cm)
            #pragma unroll
            for (int qt = 0; qt < 4; ++qt)
                acc[cm][qt] = (f32x4){0.f, 0.f, 0.f, 0.f};

        #pragma unroll 1
        for (int kk = 0; kk < 8; kk += 2) {
            const int t = ct * 8 + kk;
            bf16x8 zfh[4], zfl[4];
            LOADC(cfB, t + 1)             // in flight under MFMA(cfA)
            LOADZ(kk)
            DOMFMA(cfA)
            if (t + 2 < 32) LOADC(cfA, t + 2)   // in flight under MFMA(cfB)
            LOADZ(kk + 1)
            DOMFMA(cfB)
        }

        // fold this code-tile into the running top-2
        const int cbase = ct * 256 + w * 32;
        #pragma unroll
        for (int cm = 0; cm < 2; ++cm) {
            const int kb = cbase + cm * 16 + g * 4;
            const float4 cs4 = *reinterpret_cast<const float4*>(&csq_l[kb]);
            const float css[4] = {cs4.x, cs4.y, cs4.z, cs4.w};
            #pragma unroll
            for (int qt = 0; qt < 4; ++qt)
                #pragma unroll
                for (int r = 0; r < 4; ++r) {
                    const float d = fmaf(-2.0f, acc[cm][qt][r], css[r]);
                    if (d < b1[qt]) { b2[qt] = b1[qt]; b1[qt] = d; bidx[qt] = kb + r; }
                    else if (d < b2[qt]) b2[qt] = d;
                }
        }
    }
#undef LOADC
#undef LOADZ
#undef DOMFMA

    // --- combine the 4 quarters (same q = qt*16+cl, different codes)
    #pragma unroll
    for (int qt = 0; qt < 4; ++qt) {
        float B1 = b1[qt], B2 = b2[qt]; int BI = bidx[qt];
        #pragma unroll
        for (int m = 16; m < 64; m <<= 1) {
            const float o1 = __shfl_xor(B1, m);
            const float o2 = __shfl_xor(B2, m);
            const int   oi = __shfl_xor(BI, m);
            const float n2 = fminf(fmaxf(B1, o1), fminf(B2, o2));
            const bool sel = (o1 < B1) || (o1 == B1 && oi < BI);
            B1 = fminf(B1, o1); BI = sel ? oi : BI; B2 = n2;
        }
        if (g == 0) {
            const int q = qt * 16 + cl;
            wb1[w][q] = B1; wb2[w][q] = B2; wbi[w][q] = BI;
        }
    }
    __syncthreads();

    // --- combine 8 wave candidates, flag tight margins (LDS list)
    if (tid < 64) {
        float B1 = wb1[0][tid], B2 = wb2[0][tid]; int BI = wbi[0][tid];
        #pragma unroll
        for (int ww = 1; ww < 8; ++ww) {
            const float o1 = wb1[ww][tid], o2 = wb2[ww][tid];
            const int   oi = wbi[ww][tid];
            const float n2 = fminf(fmaxf(B1, o1), fminf(B2, o2));
            const bool sel = (o1 < B1) || (o1 == B1 && oi < BI);
            B1 = fminf(B1, o1); BI = sel ? oi : BI; B2 = n2;
        }
        qidx[tid] = BI;
        if (B2 - B1 < TAU) {
            const int pos = atomicAdd(&nf, 1);
            qf[pos] = tid;
            flagged[tid] = 1;
        }
    }
    __syncthreads();

    // --- gather (skip flagged rows; fixup writes those exclusively)
    {
        const int rr = tid >> 6;
        const int c  = (tid & 63) * 4;
        #pragma unroll
        for (int it = 0; it < 8; ++it) {
            const int q = it * 8 + rr;
            if (!flagged[q]) {
                const int k = qidx[q];
                *reinterpret_cast<float4*>(&out[(size_t)(q0 + q) * ND + c]) =
                    *reinterpret_cast<const float4*>(&cb[(size_t)k * ND + c]);
            }
        }
    }

    // --- fused exact fixup: fp64 re-solve for flagged queries.
    // Scratch carved from the dead zt (last read in the kk loops above):
    double* red  = reinterpret_cast<double*>(&zt[0][0]);    // 512 doubles (4KB)
    int*    redi = reinterpret_cast<int*>(&zt[8][0]);       // 512 ints   (2KB)
    float*  zrow = reinterpret_cast<float*>(&zt[16][0]);    // 256 floats (1KB)

    __syncthreads();                      // nf visible; zt reads all done
    const int nfl = nf;
    #pragma unroll 1
    for (int i = 0; i < nfl; ++i) {
        const int ql = qf[i];
        const int qg = q0 + ql;
        if (tid < 64)
            *reinterpret_cast<float4*>(&zrow[tid * 4]) =
                *reinterpret_cast<const float4*>(&z[(size_t)qg * ND + tid * 4]);
        __syncthreads();

        double best = 1.0e300; int bi = 0;
        #pragma unroll 1
        for (int j = 0; j < 2; ++j) {
            const int k = tid * 2 + j;
            const float* row = &cb[(size_t)k * ND];
            double s = 0.0;
            #pragma unroll 4
            for (int d = 0; d < ND; d += 4) {
                const float4 cv = *reinterpret_cast<const float4*>(&row[d]);
                const double d0 = (double)zrow[d]     - (double)cv.x;
                const double d1 = (double)zrow[d + 1] - (double)cv.y;
                const double d2 = (double)zrow[d + 2] - (double)cv.z;
                const double d3 = (double)zrow[d + 3] - (double)cv.w;
                s = fma(d0, d0, s); s = fma(d1, d1, s);
                s = fma(d2, d2, s); s = fma(d3, d3, s);
            }
            if (s < best) { best = s; bi = k; }   // ascending k: strict <
        }
        red[tid] = best; redi[tid] = bi;
        __syncthreads();
        #pragma unroll 1
        for (int m = 256; m > 0; m >>= 1) {
            if (tid < m) {
                if (red[tid + m] < red[tid] ||
                    (red[tid + m] == red[tid] && redi[tid + m] < redi[tid])) {
                    red[tid] = red[tid + m]; redi[tid] = redi[tid + m];
                }
            }
            __syncthreads();
        }
        const int kbest = redi[0];
        if (tid < 64)
            *reinterpret_cast<float4*>(&out[(size_t)qg * ND + tid * 4]) =
                *reinterpret_cast<const float4*>(&cb[(size_t)kbest * ND + tid * 4]);
        __syncthreads();
    }
}

// ------------------------------------------------- fallback (round-1) -----
// Verified-passing fp32 VALU kernel, used only if ws_size is insufficient.
__global__ __launch_bounds__(256, 2)
void vq_fallback(const float* __restrict__ z, const float* __restrict__ cb,
                 float* __restrict__ out)
{
    __shared__ float z_t[ND][64];
    __shared__ float cb_t[32][64];
    __shared__ float csq[NK];
    __shared__ int   idx_lds[64];

    const int tid = threadIdx.x;
    const int tx  = tid & 15;
    const int ty  = tid >> 4;
    const int q0  = blockIdx.x * 64;

    {
        const int r  = tid >> 6;
        const int c4 = (tid & 63) * 4;
        #pragma unroll
        for (int it = 0; it < 16; ++it) {
            const int q = it * 4 + r;
            const float4 v = *reinterpret_cast<const float4*>(
                &z[(size_t)(q0 + q) * ND + c4]);
            const float vv[4] = {v.x, v.y, v.z, v.w};
            #pragma unroll
            for (int j = 0; j < 4; ++j) {
                const int d = c4 + j;
                const int s = 4 * ((d >> 2) & 7);
                z_t[d][q ^ s] = vv[j];
            }
        }
    }
    {
        const int lane16 = tid & 15;
        const int rgrp   = tid >> 4;
        #pragma unroll 4
        for (int it = 0; it < 64; ++it) {
            const int k = it * 16 + rgrp;
            double ssum = 0.0;
            #pragma unroll
            for (int h = 0; h < 4; ++h) {
                const float4 v = *reinterpret_cast<const float4*>(
                    &cb[(size_t)k * ND + lane16 * 16 + h * 4]);
                ssum += (double)v.x * v.x + (double)v.y * v.y
                      + (double)v.z * v.z + (double)v.w * v.w;
            }
            #pragma unroll
            for (int m = 8; m >= 1; m >>= 1) ssum += __shfl_xor(ssum, m);
            if (lane16 == 0) csq[k] = (float)ssum;
        }
    }

    double bestd[4]; int besti[4];
    #pragma unroll
    for (int i = 0; i < 4; ++i) { bestd[i] = 1e300; besti[i] = 0; }

    for (int kt = 0; kt < 16; ++kt) {
        double acc[4][4];
        #pragma unroll
        for (int i = 0; i < 4; ++i)
            #pragma unroll
            for (int j = 0; j < 4; ++j) acc[i][j] = 0.0;

        for (int dc = 0; dc < 8; ++dc) {
            __syncthreads();
            {
                const int kk = tid >> 3;
                const int dd = (tid & 7) * 4;
                #pragma unroll
                for (int h = 0; h < 2; ++h) {
                    const int k = kk + h * 32;
                    const float4 v = *reinterpret_cast<const float4*>(
                        &cb[(size_t)(kt * 64 + k) * ND + dc * 32 + dd]);
                    const float vv[4] = {v.x, v.y, v.z, v.w};
                    #pragma unroll
                    for (int j = 0; j < 4; ++j) {
                        const int d = dd + j;
                        const int s = 4 * ((d >> 2) & 7);
                        cb_t[d][k ^ s] = vv[j];
                    }
                }
            }
            __syncthreads();

            float cr[4][4];
            #pragma unroll
            for (int i = 0; i < 4; ++i)
                #pragma unroll
                for (int j = 0; j < 4; ++j) cr[i][j] = 0.0f;

            #pragma unroll 8
            for (int d = 0; d < 32; ++d) {
                const int s  = 4 * ((d >> 2) & 7);
                const int dg = dc * 32 + d;
                const float4 zv4 = *reinterpret_cast<const float4*>(
                    &z_t[dg][(4 * ty) ^ s]);
                const float4 cv4 = *reinterpret_cast<const float4*>(
                    &cb_t[d][(4 * tx) ^ s]);
                const float zv[4] = {zv4.x, zv4.y, zv4.z, zv4.w};
                const float cv[4] = {cv4.x, cv4.y, cv4.z, cv4.w};
                #pragma unroll
                for (int i = 0; i < 4; ++i)
                    #pragma unroll
                    for (int j = 0; j < 4; ++j)
                        cr[i][j] = fmaf(zv[i], cv[j], cr[i][j]);
            }
            #pragma unroll
            for (int i = 0; i < 4; ++i)
                #pragma unroll
                for (int j = 0; j < 4; ++j)
                    acc[i][j] += (double)cr[i][j];
        }

        #pragma unroll
        for (int j = 0; j < 4; ++j) {
            const int k = kt * 64 + tx * 4 + j;
            const double cs = (double)csq[k];
            #pragma unroll
            for (int i = 0; i < 4; ++i) {
                const double dist = cs - 2.0 * acc[i][j];
                if (dist < bestd[i]) { bestd[i] = dist; besti[i] = k; }
            }
        }
    }

    #pragma unroll
    for (int i = 0; i < 4; ++i) {
        double bd = bestd[i]; int bi = besti[i];
        #pragma unroll
        for (int m = 8; m >= 1; m >>= 1) {
            const double od = __shfl_xor(bd, m);
            const int    oi = __shfl_xor(bi, m);
            if (od < bd || (od == bd && oi < bi)) { bd = od; bi = oi; }
        }
        if (tx == 0) idx_lds[ty * 4 + i] = bi;
    }
    __syncthreads();

    {
        const int r = tid >> 6;
        const int c = (tid & 63) * 4;
        #pragma unroll
        for (int it = 0; it < 16; ++it) {
            const int q = it * 4 + r;
            const int k = idx_lds[q];
            const float4 v = *reinterpret_cast<const float4*>(
                &cb[(size_t)k * ND + c]);
            *reinterpret_cast<float4*>(&out[(size_t)(q0 + q) * ND + c]) = v;
        }
    }
}

extern "C" void kernel_launch(void* const* d_in, const int* in_sizes, int n_in,
                              void* d_out, int out_size, void* d_ws, size_t ws_size,
                              hipStream_t stream)
{
    const float* z   = (const float*)d_in[0];   // [B,T,D] fp32
    const float* cbk = (const float*)d_in[1];   // [K,D]  fp32
    float* out = (float*)d_out;
    uint8_t* ws = (uint8_t*)d_ws;

    if (ws_size < (size_t)WS_NEEDED) {
        vq_fallback<<<NQ / 64, 256, 0, stream>>>(z, cbk, out);
        return;
    }

    vq_prep<<<NK / 4, 256, 0, stream>>>(cbk, ws);
    vq_main<<<NQ / 64, 512, 0, stream>>>(z, cbk, ws, out);
}

// Round 12
// 90.872 us; speedup vs baseline: 4.1477x; 1.0196x over previous
//
#include <hip/hip_runtime.h>
#include <stdint.h>

// VQ codebook assignment via split-precision bf16 MFMA:
//   argmin_k ||z-c_k||^2 == argmin_k (csq[k] - 2 z.c_k)
//   z.c ~= z_hi.c_hi + z_lo.c_hi + z_hi.c_lo   (bf16 hi/lo split, K_eff=768)
// Round-12: EXACT round-5 main loop (60.5us, spill-free; no cf-dbuf, no
// setprio) + fused fp64 fixup tail moved off the critical path: gather is
// unconditional (r5-identical), flags collected after it (qf carved from
// dead wb1), fixup scratch carved from dead zt, fixup OVERWRITES flagged
// rows (barrier drains vmcnt -> order safe). Graph = prep -> main.

#define NQ 32768
#define ND 256
#define NK 1024
#define TAU 0.002f   // margin threshold for the exact-fixup path

typedef short bf16x8 __attribute__((ext_vector_type(8)));
typedef float f32x4  __attribute__((ext_vector_type(4)));

// ws layout (bytes); ~1.06 MB
// cbw: ushort [64 koct][1024 codes][8]; koct 0..31 = c_hi octet, 32..63 = c_lo
#define WS_CBW 0
#define WS_CSQ (64 * 1024 * 8 * 2)       // 1 MB; then double csq[1024]
#define WS_NEEDED (WS_CSQ + 1024 * 8)

__device__ __forceinline__ ushort bf_trunc(float x) {
    return (ushort)(__builtin_bit_cast(uint32_t, x) >> 16);
}
__device__ __forceinline__ float bf_back(ushort h) {
    return __builtin_bit_cast(float, ((uint32_t)h) << 16);
}

// ---------------------------------------------------------------- prep ----
// 256 blocks x 256 threads; each wave converts one code row (4 codes/block).
__global__ __launch_bounds__(256)
void vq_prep(const float* __restrict__ cb, uint8_t* __restrict__ ws)
{
    ushort* cbw = (ushort*)(ws + WS_CBW);
    double* csq = (double*)(ws + WS_CSQ);

    const int tid  = threadIdx.x;
    const int code = blockIdx.x * 4 + (tid >> 6);
    const int lane = tid & 63;

    const int d0 = lane * 4;
    const float4 v = *reinterpret_cast<const float4*>(&cb[(size_t)code * ND + d0]);
    const float xs[4] = {v.x, v.y, v.z, v.w};

    ushort4 h4, l4;
    ushort* hp = &h4.x; ushort* lp = &l4.x;
    double ss = 0.0;
    #pragma unroll
    for (int j = 0; j < 4; ++j) {
        const ushort h = bf_trunc(xs[j]);
        hp[j] = h;
        lp[j] = bf_trunc(xs[j] - bf_back(h));
        ss += (double)xs[j] * (double)xs[j];
    }

    const int oct = d0 >> 3;             // 0..31
    const int off = d0 & 7;              // 0 or 4
    *reinterpret_cast<ushort4*>(&cbw[((size_t)oct * NK + code) * 8 + off]) = h4;
    *reinterpret_cast<ushort4*>(&cbw[((size_t)(32 + oct) * NK + code) * 8 + off]) = l4;

    #pragma unroll
    for (int m = 1; m < 64; m <<= 1) ss += __shfl_xor(ss, m);
    if (lane == 0) csq[code] = ss;
}

// ---------------------------------------------------------------- main ----
// 512 threads = 8 waves; block = 64 queries x 1024 codes (4 code-tiles).
// Wave tile: 64 q x 32 codes (cm=2 code sub-tiles x qt=4 query tiles).
__global__ __launch_bounds__(512, 4)
void vq_main(const float* __restrict__ z, const float* __restrict__ cb,
             uint8_t* __restrict__ ws, float* __restrict__ out)
{
    __shared__ alignas(16) ushort zt[64][512];  // z hi|lo, XOR-swizzled (64KB)
    __shared__ float  csq_l[NK];
    __shared__ float  wb1[8][64], wb2[8][64];
    __shared__ int    wbi[8][64];
    __shared__ int    qidx[64];
    __shared__ int    nf;

    const ushort* cbw  = (const ushort*)(ws + WS_CBW);
    const double* csqd = (const double*)(ws + WS_CSQ);

    const int tid  = threadIdx.x;
    const int lane = tid & 63;
    const int w    = tid >> 6;            // wave 0..7 -> 32-code slice per ct
    const int cl   = lane & 15;
    const int g    = lane >> 4;           // quarter 0..3 (k-octet / code-row group)
    const int q0   = blockIdx.x * 64;

    if (tid == 0) nf = 0;

    // --- stage z tile: 64q x 256d fp32 -> hi/lo bf16, swizzled 16B units
    {
        const int rr = tid >> 6;
        const int c4 = (tid & 63) * 4;
        const int uh = c4 >> 3;           // hi unit 0..31
        const int ul = (256 + c4) >> 3;   // lo unit 32..63
        #pragma unroll
        for (int it = 0; it < 8; ++it) {
            const int q = it * 8 + rr;
            const float4 v = *reinterpret_cast<const float4*>(
                &z[(size_t)(q0 + q) * ND + c4]);
            const float xs[4] = {v.x, v.y, v.z, v.w};
            ushort4 h4, l4;
            ushort* hp = &h4.x; ushort* lp = &l4.x;
            #pragma unroll
            for (int j = 0; j < 4; ++j) {
                const ushort h = bf_trunc(xs[j]);
                hp[j] = h;
                lp[j] = bf_trunc(xs[j] - bf_back(h));
            }
            const int sw = q & 7;
            *reinterpret_cast<ushort4*>(&zt[q][((uh ^ sw) << 3) + (c4 & 7)]) = h4;
            *reinterpret_cast<ushort4*>(&zt[q][((ul ^ sw) << 3) + (c4 & 7)]) = l4;
        }
    }
    #pragma unroll
    for (int i = 0; i < 2; ++i)
        csq_l[i * 512 + tid] = (float)csqd[i * 512 + tid];
    __syncthreads();

    // per-lane running top-2, one slot per q-tile (q = qt*16 + cl)
    float b1[4], b2[4]; int bidx[4];
    #pragma unroll
    for (int s = 0; s < 4; ++s) { b1[s] = 3.0e38f; b2[s] = 3.0e38f; bidx[s] = 0; }

    #pragma unroll 1
    for (int ct = 0; ct < 4; ++ct) {
        f32x4 acc[2][4];                  // [cm][qt]
        #pragma unroll
        for (int cm = 0; cm < 2; ++cm)
            #pragma unroll
            for (int qt = 0; qt < 4; ++qt)
                acc[cm][qt] = (f32x4){0.f, 0.f, 0.f, 0.f};

        const int cbase = ct * 256 + w * 32;

        #pragma unroll 1
        for (int kk = 0; kk < 8; ++kk) {
            // codebook frags (A-operand), direct from L2: hi & lo, 2 code rows
            bf16x8 cfh[2], cfl[2];
            #pragma unroll
            for (int cm = 0; cm < 2; ++cm) {
                const int code = cbase + cm * 16 + cl;
                const int oh   = kk * 4 + g;         // hi octet
                cfh[cm] = *reinterpret_cast<const bf16x8*>(
                    &cbw[((size_t)oh * NK + code) * 8]);
                cfl[cm] = *reinterpret_cast<const bf16x8*>(
                    &cbw[((size_t)(32 + oh) * NK + code) * 8]);
            }
            // z frags (B-operand) from LDS: hi & lo, 4 q-tiles
            bf16x8 zfh[4], zfl[4];
            #pragma unroll
            for (int qt = 0; qt < 4; ++qt) {
                const int q  = qt * 16 + cl;
                const int uh = (kk * 4 + g) ^ (q & 7);
                const int ul = (32 + kk * 4 + g) ^ (q & 7);
                zfh[qt] = *reinterpret_cast<const bf16x8*>(&zt[q][uh << 3]);
                zfl[qt] = *reinterpret_cast<const bf16x8*>(&zt[q][ul << 3]);
            }
            // 24 MFMA: hi*hi + hi*lo(z) + lo(c)*hi
            #pragma unroll
            for (int cm = 0; cm < 2; ++cm)
                #pragma unroll
                for (int qt = 0; qt < 4; ++qt) {
                    acc[cm][qt] = __builtin_amdgcn_mfma_f32_16x16x32_bf16(
                        cfh[cm], zfh[qt], acc[cm][qt], 0, 0, 0);
                    acc[cm][qt] = __builtin_amdgcn_mfma_f32_16x16x32_bf16(
                        cfh[cm], zfl[qt], acc[cm][qt], 0, 0, 0);
                    acc[cm][qt] = __builtin_amdgcn_mfma_f32_16x16x32_bf16(
                        cfl[cm], zfh[qt], acc[cm][qt], 0, 0, 0);
                }
        }

        // fold: lane holds, per qt, dists for codes cbase + cm*16 + g*4 + r
        #pragma unroll
        for (int cm = 0; cm < 2; ++cm) {
            const int kb = cbase + cm * 16 + g * 4;
            const float4 cs4 = *reinterpret_cast<const float4*>(&csq_l[kb]);
            const float css[4] = {cs4.x, cs4.y, cs4.z, cs4.w};
            #pragma unroll
            for (int qt = 0; qt < 4; ++qt)
                #pragma unroll
                for (int r = 0; r < 4; ++r) {
                    const float d = fmaf(-2.0f, acc[cm][qt][r], css[r]);
                    if (d < b1[qt]) { b2[qt] = b1[qt]; b1[qt] = d; bidx[qt] = kb + r; }
                    else if (d < b2[qt]) b2[qt] = d;
                }
        }
    }

    // --- combine the 4 quarters (same q = qt*16+cl, different codes)
    #pragma unroll
    for (int qt = 0; qt < 4; ++qt) {
        float B1 = b1[qt], B2 = b2[qt]; int BI = bidx[qt];
        #pragma unroll
        for (int m = 16; m < 64; m <<= 1) {
            const float o1 = __shfl_xor(B1, m);
            const float o2 = __shfl_xor(B2, m);
            const int   oi = __shfl_xor(BI, m);
            const float n2 = fminf(fmaxf(B1, o1), fminf(B2, o2));
            const bool sel = (o1 < B1) || (o1 == B1 && oi < BI);
            B1 = fminf(B1, o1); BI = sel ? oi : BI; B2 = n2;
        }
        if (g == 0) {
            const int q = qt * 16 + cl;
            wb1[w][q] = B1; wb2[w][q] = B2; wbi[w][q] = BI;
        }
    }
    __syncthreads();

    // --- combine 8 wave candidates (keep B1/B2 in regs for later flagging)
    float B1f = 0.0f, B2f = 1.0e38f;
    if (tid < 64) {
        float B1 = wb1[0][tid], B2 = wb2[0][tid]; int BI = wbi[0][tid];
        #pragma unroll
        for (int ww = 1; ww < 8; ++ww) {
            const float o1 = wb1[ww][tid], o2 = wb2[ww][tid];
            const int   oi = wbi[ww][tid];
            const float n2 = fminf(fmaxf(B1, o1), fminf(B2, o2));
            const bool sel = (o1 < B1) || (o1 == B1 && oi < BI);
            B1 = fminf(B1, o1); BI = sel ? oi : BI; B2 = n2;
        }
        qidx[tid] = BI;
        B1f = B1; B2f = B2;
    }
    __syncthreads();

    // --- gather (unconditional, r5-identical): out[q][:] = cb[idx[q]][:]
    {
        const int rr = tid >> 6;
        const int c  = (tid & 63) * 4;
        #pragma unroll
        for (int it = 0; it < 8; ++it) {
            const int q = it * 8 + rr;
            const int k = qidx[q];
            *reinterpret_cast<float4*>(&out[(size_t)(q0 + q) * ND + c]) =
                *reinterpret_cast<const float4*>(&cb[(size_t)k * ND + c]);
        }
    }

    // --- flag tight margins (after gather; qf carved from dead wb1)
    int* qf = reinterpret_cast<int*>(&wb1[0][0]);   // 64 ints, wb1 is dead
    if (tid < 64 && (B2f - B1f < TAU)) {
        const int pos = atomicAdd(&nf, 1);
        qf[pos] = tid;
    }
    __syncthreads();   // nf/qf visible; gather stores drained (vmcnt 0)

    // --- fused exact fixup: fp64 re-solve for flagged queries, overwrite out.
    // Scratch carved from the dead zt:
    double* red  = reinterpret_cast<double*>(&zt[0][0]);    // 512 doubles (4KB)
    int*    redi = reinterpret_cast<int*>(&zt[8][0]);       // 512 ints   (2KB)
    float*  zrow = reinterpret_cast<float*>(&zt[16][0]);    // 256 floats (1KB)

    const int nfl = nf;
    #pragma unroll 1
    for (int i = 0; i < nfl; ++i) {
        const int qg = q0 + qf[i];
        if (tid < 64)
            *reinterpret_cast<float4*>(&zrow[tid * 4]) =
                *reinterpret_cast<const float4*>(&z[(size_t)qg * ND + tid * 4]);
        __syncthreads();

        double best = 1.0e300; int bi = 0;
        #pragma unroll 1
        for (int j = 0; j < 2; ++j) {
            const int k = tid * 2 + j;
            const float* row = &cb[(size_t)k * ND];
            double s = 0.0;
            #pragma unroll 4
            for (int d = 0; d < ND; d += 4) {
                const float4 cv = *reinterpret_cast<const float4*>(&row[d]);
                const double d0 = (double)zrow[d]     - (double)cv.x;
                const double d1 = (double)zrow[d + 1] - (double)cv.y;
                const double d2 = (double)zrow[d + 2] - (double)cv.z;
                const double d3 = (double)zrow[d + 3] - (double)cv.w;
                s = fma(d0, d0, s); s = fma(d1, d1, s);
                s = fma(d2, d2, s); s = fma(d3, d3, s);
            }
            if (s < best) { best = s; bi = k; }   // ascending k: strict <
        }
        red[tid] = best; redi[tid] = bi;
        __syncthreads();
        #pragma unroll 1
        for (int m = 256; m > 0; m >>= 1) {
            if (tid < m) {
                if (red[tid + m] < red[tid] ||
                    (red[tid + m] == red[tid] && redi[tid + m] < redi[tid])) {
                    red[tid] = red[tid + m]; redi[tid] = redi[tid + m];
                }
            }
            __syncthreads();
        }
        const int kbest = redi[0];
        if (tid < 64)
            *reinterpret_cast<float4*>(&out[(size_t)qg * ND + tid * 4]) =
                *reinterpret_cast<const float4*>(&cb[(size_t)kbest * ND + tid * 4]);
        __syncthreads();
    }
}

// ------------------------------------------------- fallback (round-1) -----
// Verified-passing fp32 VALU kernel, used only if ws_size is insufficient.
__global__ __launch_bounds__(256, 2)
void vq_fallback(const float* __restrict__ z, const float* __restrict__ cb,
                 float* __restrict__ out)
{
    __shared__ float z_t[ND][64];
    __shared__ float cb_t[32][64];
    __shared__ float csq[NK];
    __shared__ int   idx_lds[64];

    const int tid = threadIdx.x;
    const int tx  = tid & 15;
    const int ty  = tid >> 4;
    const int q0  = blockIdx.x * 64;

    {
        const int r  = tid >> 6;
        const int c4 = (tid & 63) * 4;
        #pragma unroll
        for (int it = 0; it < 16; ++it) {
            const int q = it * 4 + r;
            const float4 v = *reinterpret_cast<const float4*>(
                &z[(size_t)(q0 + q) * ND + c4]);
            const float vv[4] = {v.x, v.y, v.z, v.w};
            #pragma unroll
            for (int j = 0; j < 4; ++j) {
                const int d = c4 + j;
                const int s = 4 * ((d >> 2) & 7);
                z_t[d][q ^ s] = vv[j];
            }
        }
    }
    {
        const int lane16 = tid & 15;
        const int rgrp   = tid >> 4;
        #pragma unroll 4
        for (int it = 0; it < 64; ++it) {
            const int k = it * 16 + rgrp;
            double ssum = 0.0;
            #pragma unroll
            for (int h = 0; h < 4; ++h) {
                const float4 v = *reinterpret_cast<const float4*>(
                    &cb[(size_t)k * ND + lane16 * 16 + h * 4]);
                ssum += (double)v.x * v.x + (double)v.y * v.y
                      + (double)v.z * v.z + (double)v.w * v.w;
            }
            #pragma unroll
            for (int m = 8; m >= 1; m >>= 1) ssum += __shfl_xor(ssum, m);
            if (lane16 == 0) csq[k] = (float)ssum;
        }
    }

    double bestd[4]; int besti[4];
    #pragma unroll
    for (int i = 0; i < 4; ++i) { bestd[i] = 1e300; besti[i] = 0; }

    for (int kt = 0; kt < 16; ++kt) {
        double acc[4][4];
        #pragma unroll
        for (int i = 0; i < 4; ++i)
            #pragma unroll
            for (int j = 0; j < 4; ++j) acc[i][j] = 0.0;

        for (int dc = 0; dc < 8; ++dc) {
            __syncthreads();
            {
                const int kk = tid >> 3;
                const int dd = (tid & 7) * 4;
                #pragma unroll
                for (int h = 0; h < 2; ++h) {
                    const int k = kk + h * 32;
                    const float4 v = *reinterpret_cast<const float4*>(
                        &cb[(size_t)(kt * 64 + k) * ND + dc * 32 + dd]);
                    const float vv[4] = {v.x, v.y, v.z, v.w};
                    #pragma unroll
                    for (int j = 0; j < 4; ++j) {
                        const int d = dd + j;
                        const int s = 4 * ((d >> 2) & 7);
                        cb_t[d][k ^ s] = vv[j];
                    }
                }
            }
            __syncthreads();

            float cr[4][4];
            #pragma unroll
            for (int i = 0; i < 4; ++i)
                #pragma unroll
                for (int j = 0; j < 4; ++j) cr[i][j] = 0.0f;

            #pragma unroll 8
            for (int d = 0; d < 32; ++d) {
                const int s  = 4 * ((d >> 2) & 7);
                const int dg = dc * 32 + d;
                const float4 zv4 = *reinterpret_cast<const float4*>(
                    &z_t[dg][(4 * ty) ^ s]);
                const float4 cv4 = *reinterpret_cast<const float4*>(
                    &cb_t[d][(4 * tx) ^ s]);
                const float zv[4] = {zv4.x, zv4.y, zv4.z, zv4.w};
                const float cv[4] = {cv4.x, cv4.y, cv4.z, cv4.w};
                #pragma unroll
                for (int i = 0; i < 4; ++i)
                    #pragma unroll
                    for (int j = 0; j < 4; ++j)
                        cr[i][j] = fmaf(zv[i], cv[j], cr[i][j]);
            }
            #pragma unroll
            for (int i = 0; i < 4; ++i)
                #pragma unroll
                for (int j = 0; j < 4; ++j)
                    acc[i][j] += (double)cr[i][j];
        }

        #pragma unroll
        for (int j = 0; j < 4; ++j) {
            const int k = kt * 64 + tx * 4 + j;
            const double cs = (double)csq[k];
            #pragma unroll
            for (int i = 0; i < 4; ++i) {
                const double dist = cs - 2.0 * acc[i][j];
                if (dist < bestd[i]) { bestd[i] = dist; besti[i] = k; }
            }
        }
    }

    #pragma unroll
    for (int i = 0; i < 4; ++i) {
        double bd = bestd[i]; int bi = besti[i];
        #pragma unroll
        for (int m = 8; m >= 1; m >>= 1) {
            const double od = __shfl_xor(bd, m);
            const int    oi = __shfl_xor(bi, m);
            if (od < bd || (od == bd && oi < bi)) { bd = od; bi = oi; }
        }
        if (tx == 0) idx_lds[ty * 4 + i] = bi;
    }
    __syncthreads();

    {
        const int r = tid >> 6;
        const int c = (tid & 63) * 4;
        #pragma unroll
        for (int it = 0; it < 16; ++it) {
            const int q = it * 4 + r;
            const int k = idx_lds[q];
            const float4 v = *reinterpret_cast<const float4*>(
                &cb[(size_t)k * ND + c]);
            *reinterpret_cast<float4*>(&out[(size_t)(q0 + q) * ND + c]) = v;
        }
    }
}

extern "C" void kernel_launch(void* const* d_in, const int* in_sizes, int n_in,
                              void* d_out, int out_size, void* d_ws, size_t ws_size,
                              hipStream_t stream)
{
    const float* z   = (const float*)d_in[0];   // [B,T,D] fp32
    const float* cbk = (const float*)d_in[1];   // [K,D]  fp32
    float* out = (float*)d_out;
    uint8_t* ws = (uint8_t*)d_ws;

    if (ws_size < (size_t)WS_NEEDED) {
        vq_fallback<<<NQ / 64, 256, 0, stream>>>(z, cbk, out);
        return;
    }

    vq_prep<<<NK / 4, 256, 0, stream>>>(cbk, ws);
    vq_main<<<NQ / 64, 512, 0, stream>>>(z, cbk, ws, out);
}

// Round 13
// 78.475 us; speedup vs baseline: 4.8029x; 1.1580x over previous
//
#include <hip/hip_runtime.h>
#include <stdint.h>

// VQ codebook assignment via split-precision bf16 MFMA:
//   argmin_k ||z-c_k||^2 == argmin_k (csq[k] - 2 z.c_k)
//   z.c ~= z_hi.c_hi + z_lo.c_hi + z_hi.c_lo   (bf16 hi/lo split, K_eff=768)
// Round-13: r5-exact main loop + O(1) fixup. Track top-3 values + top-2
// indices; margin<TAU -> owner thread fp64-compares cb[I1] vs cb[I2] only
// (lane-parallel, ~2us flat; valid since B3-B1>=TAU > 2*eps_max). Rare
// B3-B1<TAU -> block-wide full fp64 re-solve (4-acc chains). All reduction
// scratch carved from dead z-tile (LDS 69.7KB -> 2 blocks/CU).

#define NQ 32768
#define ND 256
#define NK 1024
#define TAU 0.004f   // > 2 * worst-case split-distance error (~1.6e-3)

typedef short bf16x8 __attribute__((ext_vector_type(8)));
typedef float f32x4  __attribute__((ext_vector_type(4)));

// ws layout (bytes); ~1.06 MB
// cbw: ushort [64 koct][1024 codes][8]; koct 0..31 = c_hi octet, 32..63 = c_lo
#define WS_CBW 0
#define WS_CSQ (64 * 1024 * 8 * 2)       // 1 MB; then double csq[1024]
#define WS_NEEDED (WS_CSQ + 1024 * 8)

__device__ __forceinline__ ushort bf_trunc(float x) {
    return (ushort)(__builtin_bit_cast(uint32_t, x) >> 16);
}
__device__ __forceinline__ float bf_back(ushort h) {
    return __builtin_bit_cast(float, ((uint32_t)h) << 16);
}

// ---------------------------------------------------------------- prep ----
// 256 blocks x 256 threads; each wave converts one code row (4 codes/block).
__global__ __launch_bounds__(256)
void vq_prep(const float* __restrict__ cb, uint8_t* __restrict__ ws)
{
    ushort* cbw = (ushort*)(ws + WS_CBW);
    double* csq = (double*)(ws + WS_CSQ);

    const int tid  = threadIdx.x;
    const int code = blockIdx.x * 4 + (tid >> 6);
    const int lane = tid & 63;

    const int d0 = lane * 4;
    const float4 v = *reinterpret_cast<const float4*>(&cb[(size_t)code * ND + d0]);
    const float xs[4] = {v.x, v.y, v.z, v.w};

    ushort4 h4, l4;
    ushort* hp = &h4.x; ushort* lp = &l4.x;
    double ss = 0.0;
    #pragma unroll
    for (int j = 0; j < 4; ++j) {
        const ushort h = bf_trunc(xs[j]);
        hp[j] = h;
        lp[j] = bf_trunc(xs[j] - bf_back(h));
        ss += (double)xs[j] * (double)xs[j];
    }

    const int oct = d0 >> 3;             // 0..31
    const int off = d0 & 7;              // 0 or 4
    *reinterpret_cast<ushort4*>(&cbw[((size_t)oct * NK + code) * 8 + off]) = h4;
    *reinterpret_cast<ushort4*>(&cbw[((size_t)(32 + oct) * NK + code) * 8 + off]) = l4;

    #pragma unroll
    for (int m = 1; m < 64; m <<= 1) ss += __shfl_xor(ss, m);
    if (lane == 0) csq[code] = ss;
}

// ---------------------------------------------------------------- main ----
// 512 threads = 8 waves; block = 64 queries x 1024 codes (4 code-tiles).
// Wave tile: 64 q x 32 codes (cm=2 code sub-tiles x qt=4 query tiles).
__global__ __launch_bounds__(512, 4)
void vq_main(const float* __restrict__ z, const float* __restrict__ cb,
             uint8_t* __restrict__ ws, float* __restrict__ out)
{
    __shared__ alignas(16) ushort zt[64][512];  // z hi|lo, XOR-swizzled (64KB)
    __shared__ float  csq_l[NK];
    __shared__ int    nf;

    // scratch carved from zt AFTER all MFMA reads (barrier-protected):
    float*  wb1f = reinterpret_cast<float*>(&zt[0][0]);   // [8][64]  2KB @0
    float*  wb2f = reinterpret_cast<float*>(&zt[2][0]);   // [8][64]  2KB @2K
    float*  wb3f = reinterpret_cast<float*>(&zt[4][0]);   // [8][64]  2KB @4K
    int*    wbi1 = reinterpret_cast<int*>(&zt[6][0]);     // [8][64]  2KB @6K
    int*    wbi2 = reinterpret_cast<int*>(&zt[8][0]);     // [8][64]  2KB @8K
    int*    qidx = reinterpret_cast<int*>(&zt[10][0]);    // 64 ints  @10K
    int*    qf   = reinterpret_cast<int*>(&zt[11][0]);    // 64 ints  @11K
    float*  zrow = reinterpret_cast<float*>(&zt[16][0]);  // 256 f32  @16K
    double* red  = reinterpret_cast<double*>(&zt[20][0]); // 512 f64  @20K
    int*    redi = reinterpret_cast<int*>(&zt[26][0]);    // 512 int  @26K

    const ushort* cbw  = (const ushort*)(ws + WS_CBW);
    const double* csqd = (const double*)(ws + WS_CSQ);

    const int tid  = threadIdx.x;
    const int lane = tid & 63;
    const int w    = tid >> 6;            // wave 0..7 -> 32-code slice per ct
    const int cl   = lane & 15;
    const int g    = lane >> 4;           // quarter 0..3 (k-octet / code-row group)
    const int q0   = blockIdx.x * 64;

    if (tid == 0) nf = 0;

    // --- stage z tile: 64q x 256d fp32 -> hi/lo bf16, swizzled 16B units
    {
        const int rr = tid >> 6;
        const int c4 = (tid & 63) * 4;
        const int uh = c4 >> 3;           // hi unit 0..31
        const int ul = (256 + c4) >> 3;   // lo unit 32..63
        #pragma unroll
        for (int it = 0; it < 8; ++it) {
            const int q = it * 8 + rr;
            const float4 v = *reinterpret_cast<const float4*>(
                &z[(size_t)(q0 + q) * ND + c4]);
            const float xs[4] = {v.x, v.y, v.z, v.w};
            ushort4 h4, l4;
            ushort* hp = &h4.x; ushort* lp = &l4.x;
            #pragma unroll
            for (int j = 0; j < 4; ++j) {
                const ushort h = bf_trunc(xs[j]);
                hp[j] = h;
                lp[j] = bf_trunc(xs[j] - bf_back(h));
            }
            const int sw = q & 7;
            *reinterpret_cast<ushort4*>(&zt[q][((uh ^ sw) << 3) + (c4 & 7)]) = h4;
            *reinterpret_cast<ushort4*>(&zt[q][((ul ^ sw) << 3) + (c4 & 7)]) = l4;
        }
    }
    #pragma unroll
    for (int i = 0; i < 2; ++i)
        csq_l[i * 512 + tid] = (float)csqd[i * 512 + tid];
    __syncthreads();

    // per-lane running top-3 (values) + top-2 (indices), per q-tile slot
    float b1[4], b2[4], b3[4]; int i1[4], i2[4];
    #pragma unroll
    for (int s = 0; s < 4; ++s) {
        b1[s] = 3.0e38f; b2[s] = 3.0e38f; b3[s] = 3.0e38f; i1[s] = 0; i2[s] = 0;
    }

    #pragma unroll 1
    for (int ct = 0; ct < 4; ++ct) {
        f32x4 acc[2][4];                  // [cm][qt]
        #pragma unroll
        for (int cm = 0; cm < 2; ++cm)
            #pragma unroll
            for (int qt = 0; qt < 4; ++qt)
                acc[cm][qt] = (f32x4){0.f, 0.f, 0.f, 0.f};

        const int cbase = ct * 256 + w * 32;

        #pragma unroll 1
        for (int kk = 0; kk < 8; ++kk) {
            // codebook frags (A-operand), direct from L2: hi & lo, 2 code rows
            bf16x8 cfh[2], cfl[2];
            #pragma unroll
            for (int cm = 0; cm < 2; ++cm) {
                const int code = cbase + cm * 16 + cl;
                const int oh   = kk * 4 + g;         // hi octet
                cfh[cm] = *reinterpret_cast<const bf16x8*>(
                    &cbw[((size_t)oh * NK + code) * 8]);
                cfl[cm] = *reinterpret_cast<const bf16x8*>(
                    &cbw[((size_t)(32 + oh) * NK + code) * 8]);
            }
            // z frags (B-operand) from LDS: hi & lo, 4 q-tiles
            bf16x8 zfh[4], zfl[4];
            #pragma unroll
            for (int qt = 0; qt < 4; ++qt) {
                const int q  = qt * 16 + cl;
                const int uh = (kk * 4 + g) ^ (q & 7);
                const int ul = (32 + kk * 4 + g) ^ (q & 7);
                zfh[qt] = *reinterpret_cast<const bf16x8*>(&zt[q][uh << 3]);
                zfl[qt] = *reinterpret_cast<const bf16x8*>(&zt[q][ul << 3]);
            }
            // 24 MFMA: hi*hi + hi*lo(z) + lo(c)*hi
            #pragma unroll
            for (int cm = 0; cm < 2; ++cm)
                #pragma unroll
                for (int qt = 0; qt < 4; ++qt) {
                    acc[cm][qt] = __builtin_amdgcn_mfma_f32_16x16x32_bf16(
                        cfh[cm], zfh[qt], acc[cm][qt], 0, 0, 0);
                    acc[cm][qt] = __builtin_amdgcn_mfma_f32_16x16x32_bf16(
                        cfh[cm], zfl[qt], acc[cm][qt], 0, 0, 0);
                    acc[cm][qt] = __builtin_amdgcn_mfma_f32_16x16x32_bf16(
                        cfl[cm], zfh[qt], acc[cm][qt], 0, 0, 0);
                }
        }

        // fold: k ascending within lane -> strict < keeps first occurrence
        #pragma unroll
        for (int cm = 0; cm < 2; ++cm) {
            const int kb = cbase + cm * 16 + g * 4;
            const float4 cs4 = *reinterpret_cast<const float4*>(&csq_l[kb]);
            const float css[4] = {cs4.x, cs4.y, cs4.z, cs4.w};
            #pragma unroll
            for (int qt = 0; qt < 4; ++qt)
                #pragma unroll
                for (int r = 0; r < 4; ++r) {
                    const float d = fmaf(-2.0f, acc[cm][qt][r], css[r]);
                    const int k = kb + r;
                    if (d < b1[qt]) {
                        b3[qt] = b2[qt]; b2[qt] = b1[qt]; i2[qt] = i1[qt];
                        b1[qt] = d; i1[qt] = k;
                    } else if (d < b2[qt]) {
                        b3[qt] = b2[qt]; b2[qt] = d; i2[qt] = k;
                    } else if (d < b3[qt]) {
                        b3[qt] = d;
                    }
                }
        }
    }

    __syncthreads();   // all waves done reading zt -> safe to carve scratch

    // --- combine the 4 quarters (same q = qt*16+cl, different codes)
    #pragma unroll
    for (int qt = 0; qt < 4; ++qt) {
        float B1 = b1[qt], B2 = b2[qt], B3 = b3[qt];
        int   I1 = i1[qt], I2 = i2[qt];
        #pragma unroll
        for (int m = 16; m < 64; m <<= 1) {
            const float o1 = __shfl_xor(B1, m);
            const float o2 = __shfl_xor(B2, m);
            const float o3 = __shfl_xor(B3, m);
            const int  oi1 = __shfl_xor(I1, m);
            const int  oi2 = __shfl_xor(I2, m);
            float n1, n2, n3; int ni1, ni2;
            const bool aF = (B1 < o1) || (B1 == o1 && I1 < oi1);
            if (aF) {
                n1 = B1; ni1 = I1;
                const bool a2 = (B2 < o1) || (B2 == o1 && I2 < oi1);
                if (a2) { n2 = B2; ni2 = I2;  n3 = fminf(B3, o1); }
                else    { n2 = o1; ni2 = oi1; n3 = fminf(B2, o2); }
            } else {
                n1 = o1; ni1 = oi1;
                const bool c2 = (o2 < B1) || (o2 == B1 && oi2 < I1);
                if (c2) { n2 = o2; ni2 = oi2; n3 = fminf(o3, B1); }
                else    { n2 = B1; ni2 = I1;  n3 = fminf(o2, B2); }
            }
            B1 = n1; I1 = ni1; B2 = n2; I2 = ni2; B3 = n3;
        }
        if (g == 0) {
            const int q = qt * 16 + cl;
            wb1f[w * 64 + q] = B1; wb2f[w * 64 + q] = B2; wb3f[w * 64 + q] = B3;
            wbi1[w * 64 + q] = I1; wbi2[w * 64 + q] = I2;
        }
    }
    __syncthreads();

    // --- combine 8 wave candidates (tid<64 owns query tid)
    float B1f = 0.0f, B2f = 1.0e38f, B3f = 1.0e38f;
    int   I1f = 0,    I2f = 0;
    if (tid < 64) {
        float B1 = wb1f[tid], B2 = wb2f[tid], B3 = wb3f[tid];
        int   I1 = wbi1[tid], I2 = wbi2[tid];
        #pragma unroll
        for (int ww = 1; ww < 8; ++ww) {
            const float o1 = wb1f[ww * 64 + tid];
            const float o2 = wb2f[ww * 64 + tid];
            const float o3 = wb3f[ww * 64 + tid];
            const int  oi1 = wbi1[ww * 64 + tid];
            const int  oi2 = wbi2[ww * 64 + tid];
            float n1, n2, n3; int ni1, ni2;
            const bool aF = (B1 < o1) || (B1 == o1 && I1 < oi1);
            if (aF) {
                n1 = B1; ni1 = I1;
                const bool a2 = (B2 < o1) || (B2 == o1 && I2 < oi1);
                if (a2) { n2 = B2; ni2 = I2;  n3 = fminf(B3, o1); }
                else    { n2 = o1; ni2 = oi1; n3 = fminf(B2, o2); }
            } else {
                n1 = o1; ni1 = oi1;
                const bool c2 = (o2 < B1) || (o2 == B1 && oi2 < I1);
                if (c2) { n2 = o2; ni2 = oi2; n3 = fminf(o3, B1); }
                else    { n2 = B1; ni2 = I1;  n3 = fminf(o2, B2); }
            }
            B1 = n1; I1 = ni1; B2 = n2; I2 = ni2; B3 = n3;
        }
        qidx[tid] = I1;
        B1f = B1; B2f = B2; B3f = B3; I1f = I1; I2f = I2;
    }
    __syncthreads();

    // --- gather (unconditional, r5-identical): out[q][:] = cb[idx[q]][:]
    {
        const int rr = tid >> 6;
        const int c  = (tid & 63) * 4;
        #pragma unroll
        for (int it = 0; it < 8; ++it) {
            const int q = it * 8 + rr;
            const int k = qidx[q];
            *reinterpret_cast<float4*>(&out[(size_t)(q0 + q) * ND + c]) =
                *reinterpret_cast<const float4*>(&cb[(size_t)k * ND + c]);
        }
    }
    __syncthreads();   // gather stores drained (vmcnt 0 before barrier)

    // --- O(1) fixup: owner thread exact fp64 compare of top-2 candidates.
    // Valid: any code not in {I1,I2} has approx dist >= B1+TAU, and
    // TAU > 2*eps_max, so its true dist > true min. Lane-parallel across
    // all flagged queries; overwrite only if the order flips (rare).
    const bool need2 = (tid < 64) && (B2f - B1f < TAU);
    const bool needF = (tid < 64) && (B3f - B1f < TAU);
    if (need2) {
        const int qg = q0 + tid;
        const float* zr = &z[(size_t)qg * ND];
        const float* r1 = &cb[(size_t)I1f * ND];
        const float* r2 = &cb[(size_t)I2f * ND];
        double s1a = 0.0, s1b = 0.0, s2a = 0.0, s2b = 0.0;
        #pragma unroll 4
        for (int d = 0; d < ND; d += 8) {
            const float4 za = *reinterpret_cast<const float4*>(&zr[d]);
            const float4 zb = *reinterpret_cast<const float4*>(&zr[d + 4]);
            const float4 ca = *reinterpret_cast<const float4*>(&r1[d]);
            const float4 cb4 = *reinterpret_cast<const float4*>(&r1[d + 4]);
            const float4 da = *reinterpret_cast<const float4*>(&r2[d]);
            const float4 db = *reinterpret_cast<const float4*>(&r2[d + 4]);
            double t;
            t = (double)za.x - ca.x; s1a = fma(t, t, s1a);
            t = (double)za.y - ca.y; s1a = fma(t, t, s1a);
            t = (double)za.z - ca.z; s1a = fma(t, t, s1a);
            t = (double)za.w - ca.w; s1a = fma(t, t, s1a);
            t = (double)zb.x - cb4.x; s1b = fma(t, t, s1b);
            t = (double)zb.y - cb4.y; s1b = fma(t, t, s1b);
            t = (double)zb.z - cb4.z; s1b = fma(t, t, s1b);
            t = (double)zb.w - cb4.w; s1b = fma(t, t, s1b);
            t = (double)za.x - da.x; s2a = fma(t, t, s2a);
            t = (double)za.y - da.y; s2a = fma(t, t, s2a);
            t = (double)za.z - da.z; s2a = fma(t, t, s2a);
            t = (double)za.w - da.w; s2a = fma(t, t, s2a);
            t = (double)zb.x - db.x; s2b = fma(t, t, s2b);
            t = (double)zb.y - db.y; s2b = fma(t, t, s2b);
            t = (double)zb.z - db.z; s2b = fma(t, t, s2b);
            t = (double)zb.w - db.w; s2b = fma(t, t, s2b);
        }
        const double e1 = s1a + s1b;
        const double e2 = s2a + s2b;
        const bool flip = (e2 < e1) || (e2 == e1 && I2f < I1f);
        if (flip) {
            qidx[tid] = I2f;   // keep qidx consistent for debug/consumers
            const float* src = &cb[(size_t)I2f * ND];
            float* dst = &out[(size_t)qg * ND];
            #pragma unroll 8
            for (int c = 0; c < ND; c += 4)
                *reinterpret_cast<float4*>(&dst[c]) =
                    *reinterpret_cast<const float4*>(&src[c]);
        }
    }
    // collect rare full-resolve cases (3 candidates within TAU)
    if (needF) {
        const int pos = atomicAdd(&nf, 1);
        qf[pos] = tid;
    }
    __syncthreads();

    // --- rare full fp64 re-solve (expected ~0.2% of queries)
    const int nfl = nf;
    #pragma unroll 1
    for (int i = 0; i < nfl; ++i) {
        const int qg = q0 + qf[i];
        if (tid < 64)
            *reinterpret_cast<float4*>(&zrow[tid * 4]) =
                *reinterpret_cast<const float4*>(&z[(size_t)qg * ND + tid * 4]);
        __syncthreads();

        double best = 1.0e300; int bi = 0;
        #pragma unroll 1
        for (int j = 0; j < 2; ++j) {
            const int k = tid * 2 + j;
            const float* row = &cb[(size_t)k * ND];
            double sa = 0.0, sb = 0.0, sc = 0.0, sd = 0.0;
            #pragma unroll 4
            for (int d = 0; d < ND; d += 16) {
                const float4 c0 = *reinterpret_cast<const float4*>(&row[d]);
                const float4 c1 = *reinterpret_cast<const float4*>(&row[d + 4]);
                const float4 c2 = *reinterpret_cast<const float4*>(&row[d + 8]);
                const float4 c3 = *reinterpret_cast<const float4*>(&row[d + 12]);
                double t;
                t = (double)zrow[d]      - c0.x; sa = fma(t, t, sa);
                t = (double)zrow[d + 1]  - c0.y; sa = fma(t, t, sa);
                t = (double)zrow[d + 2]  - c0.z; sa = fma(t, t, sa);
                t = (double)zrow[d + 3]  - c0.w; sa = fma(t, t, sa);
                t = (double)zrow[d + 4]  - c1.x; sb = fma(t, t, sb);
                t = (double)zrow[d + 5]  - c1.y; sb = fma(t, t, sb);
                t = (double)zrow[d + 6]  - c1.z; sb = fma(t, t, sb);
                t = (double)zrow[d + 7]  - c1.w; sb = fma(t, t, sb);
                t = (double)zrow[d + 8]  - c2.x; sc = fma(t, t, sc);
                t = (double)zrow[d + 9]  - c2.y; sc = fma(t, t, sc);
                t = (double)zrow[d + 10] - c2.z; sc = fma(t, t, sc);
                t = (double)zrow[d + 11] - c2.w; sc = fma(t, t, sc);
                t = (double)zrow[d + 12] - c3.x; sd = fma(t, t, sd);
                t = (double)zrow[d + 13] - c3.y; sd = fma(t, t, sd);
                t = (double)zrow[d + 14] - c3.z; sd = fma(t, t, sd);
                t = (double)zrow[d + 15] - c3.w; sd = fma(t, t, sd);
            }
            const double s = (sa + sb) + (sc + sd);
            if (s < best) { best = s; bi = k; }   // ascending k: strict <
        }
        red[tid] = best; redi[tid] = bi;
        __syncthreads();
        #pragma unroll 1
        for (int m = 256; m > 0; m >>= 1) {
            if (tid < m) {
                if (red[tid + m] < red[tid] ||
                    (red[tid + m] == red[tid] && redi[tid + m] < redi[tid])) {
                    red[tid] = red[tid + m]; redi[tid] = redi[tid + m];
                }
            }
            __syncthreads();
        }
        const int kbest = redi[0];
        if (tid < 64)
            *reinterpret_cast<float4*>(&out[(size_t)qg * ND + tid * 4]) =
                *reinterpret_cast<const float4*>(&cb[(size_t)kbest * ND + tid * 4]);
        __syncthreads();
    }
}

// ------------------------------------------------- fallback (round-1) -----
// Verified-passing fp32 VALU kernel, used only if ws_size is insufficient.
__global__ __launch_bounds__(256, 2)
void vq_fallback(const float* __restrict__ z, const float* __restrict__ cb,
                 float* __restrict__ out)
{
    __shared__ float z_t[ND][64];
    __shared__ float cb_t[32][64];
    __shared__ float csq[NK];
    __shared__ int   idx_lds[64];

    const int tid = threadIdx.x;
    const int tx  = tid & 15;
    const int ty  = tid >> 4;
    const int q0  = blockIdx.x * 64;

    {
        const int r  = tid >> 6;
        const int c4 = (tid & 63) * 4;
        #pragma unroll
        for (int it = 0; it < 16; ++it) {
            const int q = it * 4 + r;
            const float4 v = *reinterpret_cast<const float4*>(
                &z[(size_t)(q0 + q) * ND + c4]);
            const float vv[4] = {v.x, v.y, v.z, v.w};
            #pragma unroll
            for (int j = 0; j < 4; ++j) {
                const int d = c4 + j;
                const int s = 4 * ((d >> 2) & 7);
                z_t[d][q ^ s] = vv[j];
            }
        }
    }
    {
        const int lane16 = tid & 15;
        const int rgrp   = tid >> 4;
        #pragma unroll 4
        for (int it = 0; it < 64; ++it) {
            const int k = it * 16 + rgrp;
            double ssum = 0.0;
            #pragma unroll
            for (int h = 0; h < 4; ++h) {
                const float4 v = *reinterpret_cast<const float4*>(
                    &cb[(size_t)k * ND + lane16 * 16 + h * 4]);
                ssum += (double)v.x * v.x + (double)v.y * v.y
                      + (double)v.z * v.z + (double)v.w * v.w;
            }
            #pragma unroll
            for (int m = 8; m >= 1; m >>= 1) ssum += __shfl_xor(ssum, m);
            if (lane16 == 0) csq[k] = (float)ssum;
        }
    }

    double bestd[4]; int besti[4];
    #pragma unroll
    for (int i = 0; i < 4; ++i) { bestd[i] = 1e300; besti[i] = 0; }

    for (int kt = 0; kt < 16; ++kt) {
        double acc[4][4];
        #pragma unroll
        for (int i = 0; i < 4; ++i)
            #pragma unroll
            for (int j = 0; j < 4; ++j) acc[i][j] = 0.0;

        for (int dc = 0; dc < 8; ++dc) {
            __syncthreads();
            {
                const int kk = tid >> 3;
                const int dd = (tid & 7) * 4;
                #pragma unroll
                for (int h = 0; h < 2; ++h) {
                    const int k = kk + h * 32;
                    const float4 v = *reinterpret_cast<const float4*>(
                        &cb[(size_t)(kt * 64 + k) * ND + dc * 32 + dd]);
                    const float vv[4] = {v.x, v.y, v.z, v.w};
                    #pragma unroll
                    for (int j = 0; j < 4; ++j) {
                        const int d = dd + j;
                        const int s = 4 * ((d >> 2) & 7);
                        cb_t[d][k ^ s] = vv[j];
                    }
                }
            }
            __syncthreads();

            float cr[4][4];
            #pragma unroll
            for (int i = 0; i < 4; ++i)
                #pragma unroll
                for (int j = 0; j < 4; ++j) cr[i][j] = 0.0f;

            #pragma unroll 8
            for (int d = 0; d < 32; ++d) {
                const int s  = 4 * ((d >> 2) & 7);
                const int dg = dc * 32 + d;
                const float4 zv4 = *reinterpret_cast<const float4*>(
                    &z_t[dg][(4 * ty) ^ s]);
                const float4 cv4 = *reinterpret_cast<const float4*>(
                    &cb_t[d][(4 * tx) ^ s]);
                const float zv[4] = {zv4.x, zv4.y, zv4.z, zv4.w};
                const float cv[4] = {cv4.x, cv4.y, cv4.z, cv4.w};
                #pragma unroll
                for (int i = 0; i < 4; ++i)
                    #pragma unroll
                    for (int j = 0; j < 4; ++j)
                        cr[i][j] = fmaf(zv[i], cv[j], cr[i][j]);
            }
            #pragma unroll
            for (int i = 0; i < 4; ++i)
                #pragma unroll
                for (int j = 0; j < 4; ++j)
                    acc[i][j] += (double)cr[i][j];
        }

        #pragma unroll
        for (int j = 0; j < 4; ++j) {
            const int k = kt * 64 + tx * 4 + j;
            const double cs = (double)csq[k];
            #pragma unroll
            for (int i = 0; i < 4; ++i) {
                const double dist = cs - 2.0 * acc[i][j];
                if (dist < bestd[i]) { bestd[i] = dist; besti[i] = k; }
            }
        }
    }

    #pragma unroll
    for (int i = 0; i < 4; ++i) {
        double bd = bestd[i]; int bi = besti[i];
        #pragma unroll
        for (int m = 8; m >= 1; m >>= 1) {
            const double od = __shfl_xor(bd, m);
            const int    oi = __shfl_xor(bi, m);
            if (od < bd || (od == bd && oi < bi)) { bd = od; bi = oi; }
        }
        if (tx == 0) idx_lds[ty * 4 + i] = bi;
    }
    __syncthreads();

    {
        const int r = tid >> 6;
        const int c = (tid & 63) * 4;
        #pragma unroll
        for (int it = 0; it < 16; ++it) {
            const int q = it * 4 + r;
            const int k = idx_lds[q];
            const float4 v = *reinterpret_cast<const float4*>(
                &cb[(size_t)k * ND + c]);
            *reinterpret_cast<float4*>(&out[(size_t)(q0 + q) * ND + c]) = v;
        }
    }
}

extern "C" void kernel_launch(void* const* d_in, const int* in_sizes, int n_in,
                              void* d_out, int out_size, void* d_ws, size_t ws_size,
                              hipStream_t stream)
{
    const float* z   = (const float*)d_in[0];   // [B,T,D] fp32
    const float* cbk = (const float*)d_in[1];   // [K,D]  fp32
    float* out = (float*)d_out;
    uint8_t* ws = (uint8_t*)d_ws;

    if (ws_size < (size_t)WS_NEEDED) {
        vq_fallback<<<NQ / 64, 256, 0, stream>>>(z, cbk, out);
        return;
    }

    vq_prep<<<NK / 4, 256, 0, stream>>>(cbk, ws);
    vq_main<<<NQ / 64, 512, 0, stream>>>(z, cbk, ws, out);
}

// Round 14
// 67.617 us; speedup vs baseline: 5.5741x; 1.1606x over previous
//
#include <hip/hip_runtime.h>
#include <stdint.h>

// VQ codebook assignment via split-precision bf16 MFMA:
//   argmin_k ||z-c_k||^2 == argmin_k (csq[k] - 2 z.c_k)
//   z.c ~= z_hi.c_hi + z_lo.c_hi + z_hi.c_lo   (bf16 hi/lo split, K_eff=768)
// Round-14: r5-exact main loop + branchless top-3 fold/merges + PARALLEL
// O(1) fixup: per-wave fp64 top-2 compare (8 waves concurrent, lanes split
// rows I1/I2), rare full re-solve block-wide; both update qidx in LDS before
// ONE unconditional gather. Scratch carved from dead z-tile. TAU=0.004
// (> 2*eps_max ~1.6e-3): codes beyond top-2 provably can't win.

#define NQ 32768
#define ND 256
#define NK 1024
#define TAU 0.004f

typedef short bf16x8 __attribute__((ext_vector_type(8)));
typedef float f32x4  __attribute__((ext_vector_type(4)));

// ws layout (bytes); ~1.06 MB
// cbw: ushort [64 koct][1024 codes][8]; koct 0..31 = c_hi octet, 32..63 = c_lo
#define WS_CBW 0
#define WS_CSQ (64 * 1024 * 8 * 2)       // 1 MB; then double csq[1024]
#define WS_NEEDED (WS_CSQ + 1024 * 8)

__device__ __forceinline__ ushort bf_trunc(float x) {
    return (ushort)(__builtin_bit_cast(uint32_t, x) >> 16);
}
__device__ __forceinline__ float bf_back(ushort h) {
    return __builtin_bit_cast(float, ((uint32_t)h) << 16);
}

// ---------------------------------------------------------------- prep ----
__global__ __launch_bounds__(256)
void vq_prep(const float* __restrict__ cb, uint8_t* __restrict__ ws)
{
    ushort* cbw = (ushort*)(ws + WS_CBW);
    double* csq = (double*)(ws + WS_CSQ);

    const int tid  = threadIdx.x;
    const int code = blockIdx.x * 4 + (tid >> 6);
    const int lane = tid & 63;

    const int d0 = lane * 4;
    const float4 v = *reinterpret_cast<const float4*>(&cb[(size_t)code * ND + d0]);
    const float xs[4] = {v.x, v.y, v.z, v.w};

    ushort4 h4, l4;
    ushort* hp = &h4.x; ushort* lp = &l4.x;
    double ss = 0.0;
    #pragma unroll
    for (int j = 0; j < 4; ++j) {
        const ushort h = bf_trunc(xs[j]);
        hp[j] = h;
        lp[j] = bf_trunc(xs[j] - bf_back(h));
        ss += (double)xs[j] * (double)xs[j];
    }

    const int oct = d0 >> 3;             // 0..31
    const int off = d0 & 7;              // 0 or 4
    *reinterpret_cast<ushort4*>(&cbw[((size_t)oct * NK + code) * 8 + off]) = h4;
    *reinterpret_cast<ushort4*>(&cbw[((size_t)(32 + oct) * NK + code) * 8 + off]) = l4;

    #pragma unroll
    for (int m = 1; m < 64; m <<= 1) ss += __shfl_xor(ss, m);
    if (lane == 0) csq[code] = ss;
}

// branchless merge of two (b1,b2,b3,i1,i2) top-3 candidate sets
__device__ __forceinline__ void merge5(float& B1, float& B2, float& B3,
                                       int& I1, int& I2,
                                       float o1, float o2, float o3,
                                       int oi1, int oi2)
{
    const bool aw = (B1 < o1) || (B1 == o1 && I1 < oi1);
    const float n1 = aw ? B1 : o1;  const int ni1 = aw ? I1 : oi1;
    const float c1 = aw ? o1 : B1;  const int ci1 = aw ? oi1 : I1;  // loser 1st
    const float c2 = aw ? B2 : o2;  const int ci2 = aw ? I2 : oi2;  // winner 2nd
    const bool sw = (c2 < c1) || (c2 == c1 && ci2 < ci1);
    const float n2 = sw ? c2 : c1;  const int ni2 = sw ? ci2 : ci1;
    const float n3 = fminf(sw ? c1 : c2,
                           fminf(aw ? B3 : o3, aw ? o2 : B2));
    B1 = n1; I1 = ni1; B2 = n2; I2 = ni2; B3 = n3;
}

// ---------------------------------------------------------------- main ----
// 512 threads = 8 waves; block = 64 queries x 1024 codes (4 code-tiles).
__global__ __launch_bounds__(512, 4)
void vq_main(const float* __restrict__ z, const float* __restrict__ cb,
             uint8_t* __restrict__ ws, float* __restrict__ out)
{
    __shared__ alignas(16) ushort zt[64][512];  // z hi|lo, XOR-swizzled (64KB)
    __shared__ float  csq_l[NK];
    __shared__ int    nf;

    // scratch carved from zt AFTER all MFMA reads (barrier-protected):
    float*  wb1f = reinterpret_cast<float*>(&zt[0][0]);   // [8][64] rows 0-1
    float*  wb2f = reinterpret_cast<float*>(&zt[2][0]);
    float*  wb3f = reinterpret_cast<float*>(&zt[4][0]);
    int*    wbi1 = reinterpret_cast<int*>(&zt[6][0]);
    int*    wbi2 = reinterpret_cast<int*>(&zt[8][0]);
    int*    qidx = reinterpret_cast<int*>(&zt[10][0]);    // 64 ints
    int*    qf   = reinterpret_cast<int*>(&zt[11][0]);    // 64 ints
    float*  marg = reinterpret_cast<float*>(&zt[12][0]);  // 64 f32
    int*    mI1  = reinterpret_cast<int*>(&zt[13][0]);    // 64 ints
    int*    mI2  = reinterpret_cast<int*>(&zt[14][0]);    // 64 ints
    float*  zrow = reinterpret_cast<float*>(&zt[16][0]);  // 256 f32
    double* red  = reinterpret_cast<double*>(&zt[20][0]); // 512 f64 rows 20-23
    int*    redi = reinterpret_cast<int*>(&zt[26][0]);    // 512 int rows 26-27

    const ushort* cbw  = (const ushort*)(ws + WS_CBW);
    const double* csqd = (const double*)(ws + WS_CSQ);

    const int tid  = threadIdx.x;
    const int lane = tid & 63;
    const int w    = tid >> 6;            // wave 0..7
    const int cl   = lane & 15;
    const int g    = lane >> 4;           // quarter 0..3
    const int q0   = blockIdx.x * 64;

    if (tid == 0) nf = 0;

    // --- stage z tile: 64q x 256d fp32 -> hi/lo bf16, swizzled 16B units
    {
        const int rr = tid >> 6;
        const int c4 = (tid & 63) * 4;
        const int uh = c4 >> 3;
        const int ul = (256 + c4) >> 3;
        #pragma unroll
        for (int it = 0; it < 8; ++it) {
            const int q = it * 8 + rr;
            const float4 v = *reinterpret_cast<const float4*>(
                &z[(size_t)(q0 + q) * ND + c4]);
            const float xs[4] = {v.x, v.y, v.z, v.w};
            ushort4 h4, l4;
            ushort* hp = &h4.x; ushort* lp = &l4.x;
            #pragma unroll
            for (int j = 0; j < 4; ++j) {
                const ushort h = bf_trunc(xs[j]);
                hp[j] = h;
                lp[j] = bf_trunc(xs[j] - bf_back(h));
            }
            const int sw = q & 7;
            *reinterpret_cast<ushort4*>(&zt[q][((uh ^ sw) << 3) + (c4 & 7)]) = h4;
            *reinterpret_cast<ushort4*>(&zt[q][((ul ^ sw) << 3) + (c4 & 7)]) = l4;
        }
    }
    #pragma unroll
    for (int i = 0; i < 2; ++i)
        csq_l[i * 512 + tid] = (float)csqd[i * 512 + tid];
    __syncthreads();

    // per-lane running top-3 (values) + top-2 (indices), per q-tile slot
    float b1[4], b2[4], b3[4]; int i1[4], i2[4];
    #pragma unroll
    for (int s = 0; s < 4; ++s) {
        b1[s] = 3.0e38f; b2[s] = 3.0e38f; b3[s] = 3.0e38f; i1[s] = 0; i2[s] = 0;
    }

    #pragma unroll 1
    for (int ct = 0; ct < 4; ++ct) {
        f32x4 acc[2][4];                  // [cm][qt]
        #pragma unroll
        for (int cm = 0; cm < 2; ++cm)
            #pragma unroll
            for (int qt = 0; qt < 4; ++qt)
                acc[cm][qt] = (f32x4){0.f, 0.f, 0.f, 0.f};

        const int cbase = ct * 256 + w * 32;

        #pragma unroll 1
        for (int kk = 0; kk < 8; ++kk) {
            bf16x8 cfh[2], cfl[2];
            #pragma unroll
            for (int cm = 0; cm < 2; ++cm) {
                const int code = cbase + cm * 16 + cl;
                const int oh   = kk * 4 + g;
                cfh[cm] = *reinterpret_cast<const bf16x8*>(
                    &cbw[((size_t)oh * NK + code) * 8]);
                cfl[cm] = *reinterpret_cast<const bf16x8*>(
                    &cbw[((size_t)(32 + oh) * NK + code) * 8]);
            }
            bf16x8 zfh[4], zfl[4];
            #pragma unroll
            for (int qt = 0; qt < 4; ++qt) {
                const int q  = qt * 16 + cl;
                const int uh = (kk * 4 + g) ^ (q & 7);
                const int ul = (32 + kk * 4 + g) ^ (q & 7);
                zfh[qt] = *reinterpret_cast<const bf16x8*>(&zt[q][uh << 3]);
                zfl[qt] = *reinterpret_cast<const bf16x8*>(&zt[q][ul << 3]);
            }
            #pragma unroll
            for (int cm = 0; cm < 2; ++cm)
                #pragma unroll
                for (int qt = 0; qt < 4; ++qt) {
                    acc[cm][qt] = __builtin_amdgcn_mfma_f32_16x16x32_bf16(
                        cfh[cm], zfh[qt], acc[cm][qt], 0, 0, 0);
                    acc[cm][qt] = __builtin_amdgcn_mfma_f32_16x16x32_bf16(
                        cfh[cm], zfl[qt], acc[cm][qt], 0, 0, 0);
                    acc[cm][qt] = __builtin_amdgcn_mfma_f32_16x16x32_bf16(
                        cfl[cm], zfh[qt], acc[cm][qt], 0, 0, 0);
                }
        }

        // branchless top-3 fold (k ascending in lane -> first-occurrence ties)
        #pragma unroll
        for (int cm = 0; cm < 2; ++cm) {
            const int kb = cbase + cm * 16 + g * 4;
            const float4 cs4 = *reinterpret_cast<const float4*>(&csq_l[kb]);
            const float css[4] = {cs4.x, cs4.y, cs4.z, cs4.w};
            #pragma unroll
            for (int qt = 0; qt < 4; ++qt)
                #pragma unroll
                for (int r = 0; r < 4; ++r) {
                    const float d = fmaf(-2.0f, acc[cm][qt][r], css[r]);
                    const int k = kb + r;
                    const bool lt1 = d < b1[qt];
                    const bool lt2 = d < b2[qt];
                    i2[qt] = lt1 ? i1[qt] : (lt2 ? k : i2[qt]);
                    i1[qt] = lt1 ? k : i1[qt];
                    b3[qt] = fminf(b3[qt], fmaxf(b2[qt], d));   // uses old b2
                    b2[qt] = fminf(fmaxf(b1[qt], d), b2[qt]);   // med3(b1,b2,d)
                    b1[qt] = fminf(b1[qt], d);
                }
        }
    }

    __syncthreads();   // all waves done reading zt -> safe to carve scratch

    // --- combine the 4 quarters (same q = qt*16+cl, different codes)
    #pragma unroll
    for (int qt = 0; qt < 4; ++qt) {
        float B1 = b1[qt], B2 = b2[qt], B3 = b3[qt];
        int   I1 = i1[qt], I2 = i2[qt];
        #pragma unroll
        for (int m = 16; m < 64; m <<= 1) {
            const float o1 = __shfl_xor(B1, m);
            const float o2 = __shfl_xor(B2, m);
            const float o3 = __shfl_xor(B3, m);
            const int  oi1 = __shfl_xor(I1, m);
            const int  oi2 = __shfl_xor(I2, m);
            merge5(B1, B2, B3, I1, I2, o1, o2, o3, oi1, oi2);
        }
        if (g == 0) {
            const int q = qt * 16 + cl;
            wb1f[w * 64 + q] = B1; wb2f[w * 64 + q] = B2; wb3f[w * 64 + q] = B3;
            wbi1[w * 64 + q] = I1; wbi2[w * 64 + q] = I2;
        }
    }
    __syncthreads();

    // --- combine 8 wave candidates (tid<64 owns query tid)
    if (tid < 64) {
        float B1 = wb1f[tid], B2 = wb2f[tid], B3 = wb3f[tid];
        int   I1 = wbi1[tid], I2 = wbi2[tid];
        #pragma unroll
        for (int ww = 1; ww < 8; ++ww)
            merge5(B1, B2, B3, I1, I2,
                   wb1f[ww * 64 + tid], wb2f[ww * 64 + tid],
                   wb3f[ww * 64 + tid], wbi1[ww * 64 + tid],
                   wbi2[ww * 64 + tid]);
        qidx[tid] = I1;
        marg[tid] = B2 - B1;
        mI1[tid]  = I1;
        mI2[tid]  = I2;
        if (B3 - B1 < TAU) {           // 3 candidates within TAU: full resolve
            const int pos = atomicAdd(&nf, 1);
            qf[pos] = tid;
        }
    }
    __syncthreads();

    // --- parallel O(1) fixup: wave w handles queries w*8..w*8+7.
    // Flagged (marg<TAU): lanes<32 fp64-dist to I1, lanes>=32 to I2 (8 d/lane),
    // butterfly reduce, lane 0 flips qidx if I2 truly closer. Valid since any
    // other code's approx dist >= B1+TAU and TAU > 2*eps_max.
    #pragma unroll 1
    for (int j = 0; j < 8; ++j) {
        const int i = w * 8 + j;
        if (marg[i] >= TAU) continue;          // wave-uniform skip
        const int I1 = mI1[i], I2 = mI2[i];
        const int row = (lane < 32) ? I1 : I2;
        const int d0 = (lane & 31) * 8;
        const float* zr = &z[(size_t)(q0 + i) * ND + d0];
        const float* cr = &cb[(size_t)row * ND + d0];
        const float4 za = *reinterpret_cast<const float4*>(zr);
        const float4 zb = *reinterpret_cast<const float4*>(zr + 4);
        const float4 ca = *reinterpret_cast<const float4*>(cr);
        const float4 cb4 = *reinterpret_cast<const float4*>(cr + 4);
        double s = 0.0, t;
        t = (double)za.x - ca.x;  s = fma(t, t, s);
        t = (double)za.y - ca.y;  s = fma(t, t, s);
        t = (double)za.z - ca.z;  s = fma(t, t, s);
        t = (double)za.w - ca.w;  s = fma(t, t, s);
        t = (double)zb.x - cb4.x; s = fma(t, t, s);
        t = (double)zb.y - cb4.y; s = fma(t, t, s);
        t = (double)zb.z - cb4.z; s = fma(t, t, s);
        t = (double)zb.w - cb4.w; s = fma(t, t, s);
        #pragma unroll
        for (int m = 1; m < 32; m <<= 1) s += __shfl_xor(s, m);
        const double o = __shfl_xor(s, 32);
        if (lane == 0) {
            const double e1 = s, e2 = o;
            if ((e2 < e1) || (e2 == e1 && I2 < I1)) qidx[i] = I2;
        }
    }
    __syncthreads();

    // --- rare full fp64 re-solve (3 candidates within TAU); updates qidx
    const int nfl = nf;
    #pragma unroll 1
    for (int i = 0; i < nfl; ++i) {
        const int ql = qf[i];
        if (tid < 64)
            *reinterpret_cast<float4*>(&zrow[tid * 4]) =
                *reinterpret_cast<const float4*>(
                    &z[(size_t)(q0 + ql) * ND + tid * 4]);
        __syncthreads();

        double best = 1.0e300; int bi = 0;
        #pragma unroll 1
        for (int j = 0; j < 2; ++j) {
            const int k = tid * 2 + j;
            const float* row = &cb[(size_t)k * ND];
            double sa = 0.0, sb = 0.0, sc = 0.0, sd = 0.0;
            #pragma unroll 4
            for (int d = 0; d < ND; d += 16) {
                const float4 c0 = *reinterpret_cast<const float4*>(&row[d]);
                const float4 c1 = *reinterpret_cast<const float4*>(&row[d + 4]);
                const float4 c2 = *reinterpret_cast<const float4*>(&row[d + 8]);
                const float4 c3 = *reinterpret_cast<const float4*>(&row[d + 12]);
                double t;
                t = (double)zrow[d]      - c0.x; sa = fma(t, t, sa);
                t = (double)zrow[d + 1]  - c0.y; sa = fma(t, t, sa);
                t = (double)zrow[d + 2]  - c0.z; sa = fma(t, t, sa);
                t = (double)zrow[d + 3]  - c0.w; sa = fma(t, t, sa);
                t = (double)zrow[d + 4]  - c1.x; sb = fma(t, t, sb);
                t = (double)zrow[d + 5]  - c1.y; sb = fma(t, t, sb);
                t = (double)zrow[d + 6]  - c1.z; sb = fma(t, t, sb);
                t = (double)zrow[d + 7]  - c1.w; sb = fma(t, t, sb);
                t = (double)zrow[d + 8]  - c2.x; sc = fma(t, t, sc);
                t = (double)zrow[d + 9]  - c2.y; sc = fma(t, t, sc);
                t = (double)zrow[d + 10] - c2.z; sc = fma(t, t, sc);
                t = (double)zrow[d + 11] - c2.w; sc = fma(t, t, sc);
                t = (double)zrow[d + 12] - c3.x; sd = fma(t, t, sd);
                t = (double)zrow[d + 13] - c3.y; sd = fma(t, t, sd);
                t = (double)zrow[d + 14] - c3.z; sd = fma(t, t, sd);
                t = (double)zrow[d + 15] - c3.w; sd = fma(t, t, sd);
            }
            const double s = (sa + sb) + (sc + sd);
            if (s < best) { best = s; bi = k; }
        }
        red[tid] = best; redi[tid] = bi;
        __syncthreads();
        #pragma unroll 1
        for (int m = 256; m > 0; m >>= 1) {
            if (tid < m) {
                if (red[tid + m] < red[tid] ||
                    (red[tid + m] == red[tid] && redi[tid + m] < redi[tid])) {
                    red[tid] = red[tid + m]; redi[tid] = redi[tid + m];
                }
            }
            __syncthreads();
        }
        if (tid == 0) qidx[ql] = redi[0];
        __syncthreads();
    }

    // --- single unconditional gather: out[q][:] = cb[qidx[q]][:]
    {
        const int rr = tid >> 6;
        const int c  = (tid & 63) * 4;
        #pragma unroll
        for (int it = 0; it < 8; ++it) {
            const int q = it * 8 + rr;
            const int k = qidx[q];
            *reinterpret_cast<float4*>(&out[(size_t)(q0 + q) * ND + c]) =
                *reinterpret_cast<const float4*>(&cb[(size_t)k * ND + c]);
        }
    }
}

// ------------------------------------------------- fallback (round-1) -----
__global__ __launch_bounds__(256, 2)
void vq_fallback(const float* __restrict__ z, const float* __restrict__ cb,
                 float* __restrict__ out)
{
    __shared__ float z_t[ND][64];
    __shared__ float cb_t[32][64];
    __shared__ float csq[NK];
    __shared__ int   idx_lds[64];

    const int tid = threadIdx.x;
    const int tx  = tid & 15;
    const int ty  = tid >> 4;
    const int q0  = blockIdx.x * 64;

    {
        const int r  = tid >> 6;
        const int c4 = (tid & 63) * 4;
        #pragma unroll
        for (int it = 0; it < 16; ++it) {
            const int q = it * 4 + r;
            const float4 v = *reinterpret_cast<const float4*>(
                &z[(size_t)(q0 + q) * ND + c4]);
            const float vv[4] = {v.x, v.y, v.z, v.w};
            #pragma unroll
            for (int j = 0; j < 4; ++j) {
                const int d = c4 + j;
                const int s = 4 * ((d >> 2) & 7);
                z_t[d][q ^ s] = vv[j];
            }
        }
    }
    {
        const int lane16 = tid & 15;
        const int rgrp   = tid >> 4;
        #pragma unroll 4
        for (int it = 0; it < 64; ++it) {
            const int k = it * 16 + rgrp;
            double ssum = 0.0;
            #pragma unroll
            for (int h = 0; h < 4; ++h) {
                const float4 v = *reinterpret_cast<const float4*>(
                    &cb[(size_t)k * ND + lane16 * 16 + h * 4]);
                ssum += (double)v.x * v.x + (double)v.y * v.y
                      + (double)v.z * v.z + (double)v.w * v.w;
            }
            #pragma unroll
            for (int m = 8; m >= 1; m >>= 1) ssum += __shfl_xor(ssum, m);
            if (lane16 == 0) csq[k] = (float)ssum;
        }
    }

    double bestd[4]; int besti[4];
    #pragma unroll
    for (int i = 0; i < 4; ++i) { bestd[i] = 1e300; besti[i] = 0; }

    for (int kt = 0; kt < 16; ++kt) {
        double acc[4][4];
        #pragma unroll
        for (int i = 0; i < 4; ++i)
            #pragma unroll
            for (int j = 0; j < 4; ++j) acc[i][j] = 0.0;

        for (int dc = 0; dc < 8; ++dc) {
            __syncthreads();
            {
                const int kk = tid >> 3;
                const int dd = (tid & 7) * 4;
                #pragma unroll
                for (int h = 0; h < 2; ++h) {
                    const int k = kk + h * 32;
                    const float4 v = *reinterpret_cast<const float4*>(
                        &cb[(size_t)(kt * 64 + k) * ND + dc * 32 + dd]);
                    const float vv[4] = {v.x, v.y, v.z, v.w};
                    #pragma unroll
                    for (int j = 0; j < 4; ++j) {
                        const int d = dd + j;
                        const int s = 4 * ((d >> 2) & 7);
                        cb_t[d][k ^ s] = vv[j];
                    }
                }
            }
            __syncthreads();

            float cr[4][4];
            #pragma unroll
            for (int i = 0; i < 4; ++i)
                #pragma unroll
                for (int j = 0; j < 4; ++j) cr[i][j] = 0.0f;

            #pragma unroll 8
            for (int d = 0; d < 32; ++d) {
                const int s  = 4 * ((d >> 2) & 7);
                const int dg = dc * 32 + d;
                const float4 zv4 = *reinterpret_cast<const float4*>(
                    &z_t[dg][(4 * ty) ^ s]);
                const float4 cv4 = *reinterpret_cast<const float4*>(
                    &cb_t[d][(4 * tx) ^ s]);
                const float zv[4] = {zv4.x, zv4.y, zv4.z, zv4.w};
                const float cv[4] = {cv4.x, cv4.y, cv4.z, cv4.w};
                #pragma unroll
                for (int i = 0; i < 4; ++i)
                    #pragma unroll
                    for (int j = 0; j < 4; ++j)
                        cr[i][j] = fmaf(zv[i], cv[j], cr[i][j]);
            }
            #pragma unroll
            for (int i = 0; i < 4; ++i)
                #pragma unroll
                for (int j = 0; j < 4; ++j)
                    acc[i][j] += (double)cr[i][j];
        }

        #pragma unroll
        for (int j = 0; j < 4; ++j) {
            const int k = kt * 64 + tx * 4 + j;
            const double cs = (double)csq[k];
            #pragma unroll
            for (int i = 0; i < 4; ++i) {
                const double dist = cs - 2.0 * acc[i][j];
                if (dist < bestd[i]) { bestd[i] = dist; besti[i] = k; }
            }
        }
    }

    #pragma unroll
    for (int i = 0; i < 4; ++i) {
        double bd = bestd[i]; int bi = besti[i];
        #pragma unroll
        for (int m = 8; m >= 1; m >>= 1) {
            const double od = __shfl_xor(bd, m);
            const int    oi = __shfl_xor(bi, m);
            if (od < bd || (od == bd && oi < bi)) { bd = od; bi = oi; }
        }
        if (tx == 0) idx_lds[ty * 4 + i] = bi;
    }
    __syncthreads();

    {
        const int r = tid >> 6;
        const int c = (tid & 63) * 4;
        #pragma unroll
        for (int it = 0; it < 16; ++it) {
            const int q = it * 4 + r;
            const int k = idx_lds[q];
            const float4 v = *reinterpret_cast<const float4*>(
                &cb[(size_t)k * ND + c]);
            *reinterpret_cast<float4*>(&out[(size_t)(q0 + q) * ND + c]) = v;
        }
    }
}

extern "C" void kernel_launch(void* const* d_in, const int* in_sizes, int n_in,
                              void* d_out, int out_size, void* d_ws, size_t ws_size,
                              hipStream_t stream)
{
    const float* z   = (const float*)d_in[0];   // [B,T,D] fp32
    const float* cbk = (const float*)d_in[1];   // [K,D]  fp32
    float* out = (float*)d_out;
    uint8_t* ws = (uint8_t*)d_ws;

    if (ws_size < (size_t)WS_NEEDED) {
        vq_fallback<<<NQ / 64, 256, 0, stream>>>(z, cbk, out);
        return;
    }

    vq_prep<<<NK / 4, 256, 0, stream>>>(cbk, ws);
    vq_main<<<NQ / 64, 512, 0, stream>>>(z, cbk, ws, out);
}